// Round 6
// baseline (238.286 us; speedup 1.0000x reference)
//
#include <hip/hip_runtime.h>
#include <cstddef>
#include <cstdint>

#define EMB 1024
#define NH 16
#define HD 64
#define SEQ 2048
#define BATCH 2
#define MROWS 4096
#define LOG2E 1.4426950408889634f

typedef unsigned short u16;
typedef __attribute__((ext_vector_type(8))) short short8;
typedef __attribute__((ext_vector_type(4))) float floatx4;
typedef __attribute__((ext_vector_type(16))) float floatx16;
typedef __attribute__((ext_vector_type(2))) float f32x2;

#define MFMA32(a,b,c) __builtin_amdgcn_mfma_f32_16x16x32_bf16((a),(b),(c),0,0,0)
#define MFMA3216(a,b,c) __builtin_amdgcn_mfma_f32_32x32x16_bf16((a),(b),(c),0,0,0)

__device__ __forceinline__ u16 f2bf(float f) {           // RNE
    union { float f; uint32_t u; } v; v.f = f;
    return (u16)((v.u + 0x7fffu + ((v.u >> 16) & 1u)) >> 16);
}
// pack top-16-bits(a) (lo) | top-16-bits(b) (hi) in one v_perm
__device__ __forceinline__ uint32_t pk2u(uint32_t a, uint32_t b) {
    return __builtin_amdgcn_perm(b, a, 0x07060302u);
}
__device__ __forceinline__ float lo_f(uint32_t u) {
    union { uint32_t u; float f; } v; v.u = u << 16; return v.f;
}
__device__ __forceinline__ float hi_f(uint32_t u) {
    union { uint32_t u; float f; } v; v.u = u & 0xffff0000u; return v.f;
}
// v_permlane32_swap_b32: a' = {a.lo32, b.lo32}; b' = {a.hi32, b.hi32}
__device__ __forceinline__ void plswap(uint32_t &a, uint32_t &b) {
    asm volatile("v_permlane32_swap_b32 %0, %1" : "+v"(a), "+v"(b));
}
typedef const __attribute__((address_space(1))) void* gptr_t;
typedef __attribute__((address_space(3))) void* lptr_t;
__device__ __forceinline__ void gl2lds16(const void* g, void* l) {
    __builtin_amdgcn_global_load_lds((gptr_t)g, (lptr_t)l, 16, 0, 0);
}
// fused-reduce pair: bit-identical to reduce_k's per-word math
__device__ __forceinline__ uint32_t fuse2(uint32_t w0, uint32_t w1, uint32_t w2,
                                          uint32_t w3, float inv) {
    const float lo = (((lo_f(w0) + lo_f(w1)) + lo_f(w2)) + lo_f(w3)) * inv;
    const float hi = (((hi_f(w0) + hi_f(w1)) + hi_f(w2)) + hi_f(w3)) * inv;
    return (uint32_t)f2bf(lo) | ((uint32_t)f2bf(hi) << 16);
}

// ---------------------------------------------------------------------------
// Fused convert: z<4 -> W[z] fp32 [K][N] -> W^T [N][K] bf16 (z==0 scaled by
// log2e/8); z==4 -> x fp32 -> bf16 (grid-stride over the 4M plane).
// ---------------------------------------------------------------------------
__global__ __launch_bounds__(256) void cvt_all_k(
    const float* __restrict__ x,
    const float* __restrict__ W0, const float* __restrict__ W1,
    const float* __restrict__ W2, const float* __restrict__ W3,
    u16* __restrict__ Wt4, u16* __restrict__ xh) {
    const int z = blockIdx.z;
    const int tid = threadIdx.x;
    if (z == 4) {
        const int nb = gridDim.x * gridDim.y;
        const int bid = blockIdx.y * gridDim.x + blockIdx.x;
        const int stride = nb * 256 * 8;
        for (int i = (bid * 256 + tid) * 8; i < MROWS * EMB; i += stride) {
            float4 a = *(const float4*)(x + i);
            float4 b = *(const float4*)(x + i + 4);
            alignas(16) u16 o[8] = {f2bf(a.x), f2bf(a.y), f2bf(a.z), f2bf(a.w),
                                    f2bf(b.x), f2bf(b.y), f2bf(b.z), f2bf(b.w)};
            *(uint4*)(xh + i) = *(const uint4*)o;
        }
        return;
    }
    const float* W = (z == 0) ? W0 : (z == 1) ? W1 : (z == 2) ? W2 : W3;
    const float scale = (z == 0) ? 0.125f * LOG2E : 1.0f;
    u16* dst = Wt4 + (size_t)z * 1048576;
    __shared__ float Lf[64][65];
    const int kt = blockIdx.y * 64, nt = blockIdx.x * 64;
    {
        const int r = tid >> 2, c4 = (tid & 3) * 16;
        const float* src = W + (size_t)(kt + r) * EMB + nt + c4;
        #pragma unroll
        for (int i = 0; i < 16; i += 4) {
            float4 v = *(const float4*)(src + i);
            Lf[r][c4 + i + 0] = v.x; Lf[r][c4 + i + 1] = v.y;
            Lf[r][c4 + i + 2] = v.z; Lf[r][c4 + i + 3] = v.w;
        }
    }
    __syncthreads();
    const int n = tid >> 2, k4 = (tid & 3) * 16;
    alignas(16) u16 hb[16];
    #pragma unroll
    for (int i = 0; i < 16; ++i) hb[i] = f2bf(Lf[k4 + i][n] * scale);
    const size_t o = (size_t)(nt + n) * EMB + kt + k4;
    *(uint4*)(dst + o) = *(const uint4*)hb;
    *(uint4*)(dst + o + 8) = *(const uint4*)(hb + 8);
}

// ---------------------------------------------------------------------------
// QKV GEMM: 128x128 tile, BK=32, double-buffered (1 barrier/iter).
// XCD chunk remap (value-identical block->tile permutation).
// ---------------------------------------------------------------------------
__global__ __launch_bounds__(256) void gemm_qkv_k(
    const u16* __restrict__ xh, const u16* __restrict__ Wt4,
    const float* __restrict__ b0, const float* __restrict__ b1,
    const float* __restrict__ b2,
    u16* __restrict__ Q, u16* __restrict__ K, u16* __restrict__ V) {
    const int flat = blockIdx.x + 8 * blockIdx.y + 256 * blockIdx.z;
    const int xcd = flat & 7, i6 = flat >> 3;       // i6: 0..95
    const int z = i6 >> 5, j = i6 & 31;             // z 0..2, j 0..31
    const int cm = xcd & 3, cn = xcd >> 2;
    const int bm = (cm * 8 + (j >> 2)) * 128;       // 32 bm tiles
    const int bn = (cn * 4 + (j & 3)) * 128;        // 8 bn tiles

    const u16* Wt = Wt4 + (size_t)z * 1048576;
    const float* bias = (z == 0) ? b0 : (z == 1) ? b1 : b2;
    u16* out = (z == 0) ? Q : (z == 1) ? K : V;
    const float bscale = (z == 0) ? 0.125f * LOG2E : 1.0f;
    __shared__ alignas(16) u16 As[2][4096];
    __shared__ alignas(16) u16 Bs[2][4096];
    const int tid = threadIdx.x;
    const int lane = tid & 63, w = tid >> 6;
    const int l15 = lane & 15, quad = lane >> 4;
    const int wm = (w & 1) * 64, wn = (w >> 1) * 64;

    floatx4 acc[4][4];
    const floatx4 zf = {0.f, 0.f, 0.f, 0.f};
    #pragma unroll
    for (int mt = 0; mt < 4; ++mt)
        #pragma unroll
        for (int nt = 0; nt < 4; ++nt) acc[mt][nt] = zf;

    const int c0 = tid, c1 = tid + 256;
    const int r0 = c0 >> 2, p0 = c0 & 3, cc0 = (p0 - r0 - (r0 >> 2)) & 3;
    const int r1 = c1 >> 2, p1 = c1 & 3, cc1 = (p1 - r1 - (r1 >> 2)) & 3;
    const u16* ag0 = xh + (size_t)(bm + r0) * EMB + cc0 * 8;
    const u16* ag1 = xh + (size_t)(bm + r1) * EMB + cc1 * 8;
    const u16* bg0 = Wt + (size_t)(bn + r0) * EMB + cc0 * 8;
    const u16* bg1 = Wt + (size_t)(bn + r1) * EMB + cc1 * 8;

    #define QSTAGE(bf, kk) do { \
        gl2lds16(ag0 + (kk), &As[bf][c0 * 8]); gl2lds16(ag1 + (kk), &As[bf][c1 * 8]); \
        gl2lds16(bg0 + (kk), &Bs[bf][c0 * 8]); gl2lds16(bg1 + (kk), &Bs[bf][c1 * 8]); } while (0)

    QSTAGE(0, 0);
    __syncthreads();
    for (int kt = 0; kt < EMB; kt += 32) {
        const int cur = (kt >> 5) & 1;
        if (kt + 32 < EMB) QSTAGE(cur ^ 1, kt + 32);
        short8 af[4], bf[4];
        #pragma unroll
        for (int t = 0; t < 4; ++t) {
            const int ra = wm + t * 16 + l15;
            const int rb = wn + t * 16 + l15;
            af[t] = *(const short8*)&As[cur][ra * 32 + ((quad + ra + (ra >> 2)) & 3) * 8];
            bf[t] = *(const short8*)&Bs[cur][rb * 32 + ((quad + rb + (rb >> 2)) & 3) * 8];
        }
        __builtin_amdgcn_s_setprio(1);
        #pragma unroll
        for (int mt = 0; mt < 4; ++mt)
            #pragma unroll
            for (int nt = 0; nt < 4; ++nt)
                acc[mt][nt] = MFMA32(af[mt], bf[nt], acc[mt][nt]);
        __builtin_amdgcn_s_setprio(0);
        __syncthreads();   // drains this iter's prefetch into buf cur^1
    }

    #pragma unroll
    for (int nt = 0; nt < 4; ++nt) {
        const int col = bn + wn + nt * 16 + l15;
        const float bv = bias[col] * bscale;
        #pragma unroll
        for (int mt = 0; mt < 4; ++mt) {
            const int row = bm + wm + mt * 16 + quad * 4;
            #pragma unroll
            for (int r = 0; r < 4; ++r)
                out[(size_t)(row + r) * EMB + col] = f2bf(acc[mt][nt][r] + bv);
        }
    }
}

// ---------------------------------------------------------------------------
// O-projection with FUSED split-K reduce: A = (N0+N1+N2+N3)/sum(Lp planes),
// computed bit-identically to the old reduce_k during register-staging, then
// ds_write_b128 into the same swizzled LDS layout. B via global_load_lds.
// 128x64 tile, BK=32, dbuf, 1 barrier/iter (T14 async-stage split: loads
// issued before MFMA, processed after). fp32 out + bias.
// XCD chunk remap (value-identical): 8bm x 8bn per XCD.
// ---------------------------------------------------------------------------
__global__ __launch_bounds__(256) void gemm_o_k(
    const u16* __restrict__ Np0, const u16* __restrict__ Np1,
    const u16* __restrict__ Np2, const u16* __restrict__ Np3,
    const float* __restrict__ Lp,
    const u16* __restrict__ Wt,
    const float* __restrict__ bias, float* __restrict__ out) {
    const int flat = blockIdx.x + 16 * blockIdx.y;  // grid (16,32,1)
    const int xcd = flat & 7, i6 = flat >> 3;       // i6: 0..63
    const int cm = xcd & 3, cn = xcd >> 2;
    const int bm = (cm * 8 + (i6 >> 3)) * 128;      // 32 bm tiles
    const int bn = (cn * 8 + (i6 & 7)) * 64;        // 16 bn tiles
    __shared__ alignas(16) u16 As[2][4096];   // 128 x 32 x2
    __shared__ alignas(16) u16 Bs[2][2048];   // 64 x 32 x2
    const int tid = threadIdx.x;
    const int lane = tid & 63, w = tid >> 6;
    const int l15 = lane & 15, quad = lane >> 4;
    const int wm = w * 32;
    const int PL = MROWS * NH;   // 65536 per Lp plane

    floatx4 acc[2][4];
    const floatx4 zf = {0.f, 0.f, 0.f, 0.f};
    #pragma unroll
    for (int mt = 0; mt < 2; ++mt)
        #pragma unroll
        for (int nt = 0; nt < 4; ++nt) acc[mt][nt] = zf;

    const int c0 = tid, c1 = tid + 256;
    const int r0 = c0 >> 2, p0 = c0 & 3, cc0 = (p0 - r0 - (r0 >> 2)) & 3;
    const int r1 = c1 >> 2, p1 = c1 & 3, cc1 = (p1 - r1 - (r1 >> 2)) & 3;
    const size_t ga0 = (size_t)(bm + r0) * EMB + cc0 * 8;
    const size_t ga1 = (size_t)(bm + r1) * EMB + cc1 * 8;
    const size_t lx0 = (size_t)(bm + r0) * NH;
    const size_t lx1 = (size_t)(bm + r1) * NH;
    const u16* bg0 = Wt + (size_t)(bn + r0) * EMB + cc0 * 8;   // first 256 slots

    uint4 s0n0, s0n1, s0n2, s0n3, s1n0, s1n1, s1n2, s1n3;
    float inv0, inv1;

    // load A partial regs + lsum for K-chunk kk (head = kk>>6, uniform: kk%64
    // in {0,32} and chunk offsets <32 never cross a 64 boundary)
    #define OLOADA(kk) do { \
        s0n0 = *(const uint4*)(Np0 + ga0 + (kk)); \
        s0n1 = *(const uint4*)(Np1 + ga0 + (kk)); \
        s0n2 = *(const uint4*)(Np2 + ga0 + (kk)); \
        s0n3 = *(const uint4*)(Np3 + ga0 + (kk)); \
        s1n0 = *(const uint4*)(Np0 + ga1 + (kk)); \
        s1n1 = *(const uint4*)(Np1 + ga1 + (kk)); \
        s1n2 = *(const uint4*)(Np2 + ga1 + (kk)); \
        s1n3 = *(const uint4*)(Np3 + ga1 + (kk)); \
        const int hh_ = (kk) >> 6; \
        const float l0_ = ((Lp[lx0 + hh_] + Lp[PL + lx0 + hh_]) + \
                           Lp[2 * PL + lx0 + hh_]) + Lp[3 * PL + lx0 + hh_]; \
        const float l1_ = ((Lp[lx1 + hh_] + Lp[PL + lx1 + hh_]) + \
                           Lp[2 * PL + lx1 + hh_]) + Lp[3 * PL + lx1 + hh_]; \
        inv0 = 1.f / l0_; inv1 = 1.f / l1_; } while (0)

    // combine partials -> bf16 (bit-identical to reduce_k) -> LDS
    #define OPROC(bf) do { \
        uint4 o0, o1; \
        o0.x = fuse2(s0n0.x, s0n1.x, s0n2.x, s0n3.x, inv0); \
        o0.y = fuse2(s0n0.y, s0n1.y, s0n2.y, s0n3.y, inv0); \
        o0.z = fuse2(s0n0.z, s0n1.z, s0n2.z, s0n3.z, inv0); \
        o0.w = fuse2(s0n0.w, s0n1.w, s0n2.w, s0n3.w, inv0); \
        o1.x = fuse2(s1n0.x, s1n1.x, s1n2.x, s1n3.x, inv1); \
        o1.y = fuse2(s1n0.y, s1n1.y, s1n2.y, s1n3.y, inv1); \
        o1.z = fuse2(s1n0.z, s1n1.z, s1n2.z, s1n3.z, inv1); \
        o1.w = fuse2(s1n0.w, s1n1.w, s1n2.w, s1n3.w, inv1); \
        *((uint4*)&As[bf][c0 * 8]) = o0; \
        *((uint4*)&As[bf][c1 * 8]) = o1; } while (0)

    #define OSTAGEB(bf, kk) do { \
        if (c0 < 256) gl2lds16(bg0 + (kk), &Bs[bf][c0 * 8]); } while (0)

    OLOADA(0); OSTAGEB(0, 0);
    OPROC(0);
    __syncthreads();   // ds_writes visible + B gl2lds drained
    for (int kt = 0; kt < EMB; kt += 32) {
        const int cur = (kt >> 5) & 1;
        const bool more = (kt + 32 < EMB);
        if (more) { OLOADA(kt + 32); OSTAGEB(cur ^ 1, kt + 32); }
        short8 af[2], bf[4];
        #pragma unroll
        for (int t = 0; t < 2; ++t) {
            const int ra = wm + t * 16 + l15;
            af[t] = *(const short8*)&As[cur][ra * 32 + ((quad + ra + (ra >> 2)) & 3) * 8];
        }
        #pragma unroll
        for (int t = 0; t < 4; ++t) {
            const int rb = t * 16 + l15;
            bf[t] = *(const short8*)&Bs[cur][rb * 32 + ((quad + rb + (rb >> 2)) & 3) * 8];
        }
        __builtin_amdgcn_s_setprio(1);
        #pragma unroll
        for (int mt = 0; mt < 2; ++mt)
            #pragma unroll
            for (int nt = 0; nt < 4; ++nt)
                acc[mt][nt] = MFMA32(af[mt], bf[nt], acc[mt][nt]);
        __builtin_amdgcn_s_setprio(0);
        if (more) OPROC(cur ^ 1);   // hides partial-combine VALU under waits
        __syncthreads();
    }

    #pragma unroll
    for (int nt = 0; nt < 4; ++nt) {
        const int col = bn + nt * 16 + l15;
        const float bv = bias[col];
        #pragma unroll
        for (int mt = 0; mt < 2; ++mt) {
            const int row = bm + wm + mt * 16 + quad * 4;
            #pragma unroll
            for (int r = 0; r < 4; ++r)
                out[(size_t)(row + r) * EMB + col] = acc[mt][nt][r] + bv;
        }
    }
}

// ---------------------------------------------------------------------------
// V [B*S][E] bf16 -> Vt [B][H][D][S] bf16 (coalesced via LDS)
// ---------------------------------------------------------------------------
__global__ __launch_bounds__(256) void vtrans_k(const u16* __restrict__ V,
                                                u16* __restrict__ Vt) {
    const int tt = blockIdx.x, h = blockIdx.y, b = blockIdx.z;
    __shared__ u16 Lt[64][72];
    const int tid = threadIdx.x;
    {
        const int r = tid >> 2, c4 = (tid & 3) * 16;
        const u16* src = V + (size_t)(b * SEQ + tt * 64 + r) * EMB + h * HD + c4;
        alignas(16) u16 buf[16];
        *(uint4*)buf = *(const uint4*)src;
        *(uint4*)(buf + 8) = *(const uint4*)(src + 8);
        #pragma unroll
        for (int i = 0; i < 16; ++i) Lt[c4 + i][r] = buf[i];
    }
    __syncthreads();
    const int d = tid >> 2, t4 = (tid & 3) * 16;
    u16* dst = Vt + ((size_t)((b * NH + h) * HD + d)) * SEQ + tt * 64 + t4;
    *(uint4*)dst = *(const uint4*)&Lt[d][t4];
    *(uint4*)(dst + 8) = *(const uint4*)&Lt[d][t4 + 8];
}

// ---------------------------------------------------------------------------
// Flash attention v12 (round-5 PASSING version, verbatim): split-K x4 over t,
// bf16 partials, ones-MFMA l, packed Schraudolph, dbuf 1-barrier, XCD group
// remap (16 whole (h,b,sp) groups per XCD -> K/V L2-resident).
// ---------------------------------------------------------------------------
__global__ __launch_bounds__(256) void flash_k(
    const u16* __restrict__ Q, const u16* __restrict__ K,
    const u16* __restrict__ Vt,
    u16* __restrict__ Np0, u16* __restrict__ Np1,
    u16* __restrict__ Np2, u16* __restrict__ Np3,
    float* __restrict__ Lp) {
    // flat = bx + 16*by + 256*bz (HW dispatch order); xcd = flat%8
    const int flat = blockIdx.x + 16 * blockIdx.y + 256 * blockIdx.z;
    const int xcd = flat & 7, idx = flat >> 3;       // idx 0..255
    const int gid = xcd * 16 + (idx >> 4);           // group 0..127 = (h,b,sp)
    const int qt = idx & 15;
    const int h = gid & 15, zz = gid >> 4;           // zz 0..7
    const int b = zz >> 2, sp = zz & 3;
    const int t0 = sp * (SEQ / 4);
    __shared__ alignas(16) u16 Ks[2][4096];   // [t64][d64] 128B rows, swizzled
    __shared__ alignas(16) u16 Vs[2][4096];   // [d64][t64] 128B rows, swizzled
    const int tid = threadIdx.x;
    const int lane = tid & 63, w = tid >> 6;
    const int l31 = lane & 31, hf = lane >> 5;

    // Q B-frags: qb[c][j] = Q[q][h*64 + c*16 + hf*8 + j], q = qt*128+w*32+l31
    const u16* qp = Q + (size_t)(b * SEQ + qt * 128 + w * 32 + l31) * EMB
                    + h * HD + hf * 8;
    short8 qb[4];
    #pragma unroll
    for (int c = 0; c < 4; ++c) qb[c] = *(const short8*)(qp + c * 16);

    const floatx16 z16 = {0.f, 0.f, 0.f, 0.f, 0.f, 0.f, 0.f, 0.f,
                          0.f, 0.f, 0.f, 0.f, 0.f, 0.f, 0.f, 0.f};
    floatx16 oacc[2];
    oacc[0] = z16; oacc[1] = z16;
    floatx16 lacc = z16;
    const short8 ones8 = {0x3F80, 0x3F80, 0x3F80, 0x3F80,
                          0x3F80, 0x3F80, 0x3F80, 0x3F80};   // bf16 1.0

    // staging: slot s -> row r=s>>3, pos p=s&7, source chunk c=(p-r)&7
    const int s0 = tid, s1 = tid + 256;
    const int kr0 = s0 >> 3, kc0 = ((s0 & 7) - kr0) & 7;
    const int kr1 = s1 >> 3, kc1 = ((s1 & 7) - kr1) & 7;
    const u16* kg0 = K + (size_t)(b * SEQ + t0 + kr0) * EMB + h * HD + kc0 * 8;
    const u16* kg1 = K + (size_t)(b * SEQ + t0 + kr1) * EMB + h * HD + kc1 * 8;
    const u16* vg0 = Vt + ((size_t)((b * NH + h) * HD + kr0)) * SEQ + t0 + kc0 * 8;
    const u16* vg1 = Vt + ((size_t)((b * NH + h) * HD + kr1)) * SEQ + t0 + kc1 * 8;

    #define FSTAGE(bf, kk) do { \
        gl2lds16(kg0 + (size_t)(kk) * 64 * EMB, &Ks[bf][s0 * 8]); \
        gl2lds16(kg1 + (size_t)(kk) * 64 * EMB, &Ks[bf][s1 * 8]); \
        gl2lds16(vg0 + (kk) * 64, &Vs[bf][s0 * 8]); \
        gl2lds16(vg1 + (kk) * 64, &Vs[bf][s1 * 8]); } while (0)

    const int NT = SEQ / 4 / 64;   // 8
    FSTAGE(0, 0);
    __syncthreads();
    for (int kt = 0; kt < NT; ++kt) {
        const int cur = kt & 1;
        if (kt + 1 < NT) FSTAGE(cur ^ 1, kt + 1);

        // St = K Q^T per 32-t tile; exp; pack PV A-frags pa[g] (t=g*16..+15)
        short8 pa[4];
        #pragma unroll
        for (int tt = 0; tt < 2; ++tt) {
            floatx16 st = z16;
            const int r = tt * 32 + l31;
            __builtin_amdgcn_s_setprio(1);
            #pragma unroll
            for (int c = 0; c < 4; ++c) {
                const int jc = c * 2 + hf;
                const short8 ka = *(const short8*)&Ks[cur][r * 64 + ((jc + r) & 7) * 8];
                st = MFMA3216(ka, qb[c], st);
            }
            __builtin_amdgcn_s_setprio(0);
            // packed Schraudolph 2^s: bits = (int)(s*2^23 + C) via v_pk_fma
            uint32_t e[16];
            #pragma unroll
            for (int i = 0; i < 16; i += 2) {
                f32x2 v = {st[i], st[i + 1]};
                v = v * 8388608.0f + 1064992512.0f;
                e[i] = (uint32_t)(int)v.x;
                e[i + 1] = (uint32_t)(int)v.y;
            }
            #pragma unroll
            for (int c = 0; c < 2; ++c) {
                uint32_t w0 = pk2u(e[c * 8 + 0], e[c * 8 + 1]);
                uint32_t w1 = pk2u(e[c * 8 + 2], e[c * 8 + 3]);
                uint32_t w2 = pk2u(e[c * 8 + 4], e[c * 8 + 5]);
                uint32_t w3 = pk2u(e[c * 8 + 6], e[c * 8 + 7]);
                plswap(w0, w2);   // -> word0, word2
                plswap(w1, w3);   // -> word1, word3
                union { uint32_t uu[4]; short8 s; } pk_;
                pk_.uu[0] = w0; pk_.uu[1] = w1; pk_.uu[2] = w2; pk_.uu[3] = w3;
                pa[tt * 2 + c] = pk_.s;
            }
        }

        // O += P^T V ; l += P^T 1 (ones-MFMA: same truncated bits as numerator)
        __builtin_amdgcn_s_setprio(1);
        #pragma unroll
        for (int dt = 0; dt < 2; ++dt) {
            const int vr = dt * 32 + l31;
            #pragma unroll
            for (int g = 0; g < 4; ++g) {
                const int jc = g * 2 + hf;
                const short8 vb = *(const short8*)&Vs[cur][vr * 64 + ((jc + vr) & 7) * 8];
                oacc[dt] = MFMA3216(pa[g], vb, oacc[dt]);
            }
        }
        #pragma unroll
        for (int g = 0; g < 4; ++g) lacc = MFMA3216(pa[g], ones8, lacc);
        __builtin_amdgcn_s_setprio(0);

        __syncthreads();   // drains this iter's prefetch into buf cur^1
    }

    u16* np = (sp == 0) ? Np0 : (sp == 1) ? Np1 : (sp == 2) ? Np2 : Np3;
    float* lp = Lp + (size_t)sp * (MROWS * NH);

    // l store: lacc rows are col-replicated; lanes with l31==0 own all 16 rows
    if (l31 == 0) {
        #pragma unroll
        for (int r = 0; r < 16; ++r) {
            const int qloc = (r & 3) + 8 * (r >> 2) + 4 * hf;
            const int qrow = qt * 128 + w * 32 + qloc;
            lp[(size_t)(b * SEQ + qrow) * NH + h] = lacc[r];
        }
    }

    // numerator: C layout col=l31 (d), row=(r&3)+8*(r>>2)+4*hf (q)
    #pragma unroll
    for (int dt = 0; dt < 2; ++dt)
        #pragma unroll
        for (int r = 0; r < 16; ++r) {
            const int qloc = (r & 3) + 8 * (r >> 2) + 4 * hf;
            const size_t o =
                (size_t)(b * SEQ + qt * 128 + w * 32 + qloc) * EMB
                + h * HD + dt * 32 + l31;
            np[o] = f2bf(oacc[dt][r]);
        }
}

// ---------------------------------------------------------------------------
extern "C" void kernel_launch(void* const* d_in, const int* in_sizes, int n_in,
                              void* d_out, int out_size, void* d_ws, size_t ws_size,
                              hipStream_t stream) {
    const float* x  = (const float*)d_in[0];
    const float* Wq = (const float*)d_in[1];
    const float* bq = (const float*)d_in[2];
    const float* Wk = (const float*)d_in[3];
    const float* bk = (const float*)d_in[4];
    const float* Wv = (const float*)d_in[5];
    const float* bv = (const float*)d_in[6];
    const float* Wo = (const float*)d_in[7];
    const float* bo = (const float*)d_in[8];

    u16* ws16 = (u16*)d_ws;
    const size_t P4 = (size_t)MROWS * EMB;   // 4M elems (8 MB)
    u16* xh  = ws16;                 // x bf16; dead after gemm_qkv -> N0
    u16* Qb  = ws16 + P4;            // Q; dead after flash
    u16* Kb  = ws16 + 2 * P4;
    u16* Vb  = ws16 + 3 * P4;        // V row-major; dead after vtrans -> N1
    u16* Vtb = ws16 + 4 * P4;        // V transposed [B][H][D][S]
    u16* Wt4 = ws16 + 5 * P4;        // 4 planes of 1M: Wq^T*log2e/8, Wk^T, Wv^T, Wo^T
    u16* N2  = ws16 + 6 * P4;
    u16* N3  = ws16 + 7 * P4;
    float* Lp = (float*)(ws16 + 8 * P4);   // 4 x 65536 floats (1 MB)

    cvt_all_k<<<dim3(16, 16, 5), 256, 0, stream>>>(x, Wq, Wk, Wv, Wo, Wt4, xh);
    gemm_qkv_k<<<dim3(8, 32, 3), 256, 0, stream>>>(xh, Wt4, bq, bk, bv, Qb, Kb, Vb);
    vtrans_k<<<dim3(32, 16, 2), 256, 0, stream>>>(Vb, Vtb);
    flash_k<<<dim3(16, 16, 8), 256, 0, stream>>>(Qb, Kb, Vtb, xh, Vb, N2, N3, Lp);
    gemm_o_k<<<dim3(16, 32, 1), 256, 0, stream>>>(xh, Vb, N2, N3, Lp,
                                                  Wt4 + 3 * 1048576, bo,
                                                  (float*)d_out);
}

// Round 7
// 212.426 us; speedup vs baseline: 1.1217x; 1.1217x over previous
//
#include <hip/hip_runtime.h>
#include <cstddef>
#include <cstdint>

#define EMB 1024
#define NH 16
#define HD 64
#define SEQ 2048
#define BATCH 2
#define MROWS 4096
#define LOG2E 1.4426950408889634f

typedef unsigned short u16;
typedef __attribute__((ext_vector_type(8))) short short8;
typedef __attribute__((ext_vector_type(4))) float floatx4;
typedef __attribute__((ext_vector_type(16))) float floatx16;
typedef __attribute__((ext_vector_type(2))) float f32x2;

#define MFMA32(a,b,c) __builtin_amdgcn_mfma_f32_16x16x32_bf16((a),(b),(c),0,0,0)
#define MFMA3216(a,b,c) __builtin_amdgcn_mfma_f32_32x32x16_bf16((a),(b),(c),0,0,0)

__device__ __forceinline__ u16 f2bf(float f) {           // RNE
    union { float f; uint32_t u; } v; v.f = f;
    return (u16)((v.u + 0x7fffu + ((v.u >> 16) & 1u)) >> 16);
}
// pack top-16-bits(a) (lo) | top-16-bits(b) (hi) in one v_perm
__device__ __forceinline__ uint32_t pk2u(uint32_t a, uint32_t b) {
    return __builtin_amdgcn_perm(b, a, 0x07060302u);
}
__device__ __forceinline__ float lo_f(uint32_t u) {
    union { uint32_t u; float f; } v; v.u = u << 16; return v.f;
}
__device__ __forceinline__ float hi_f(uint32_t u) {
    union { uint32_t u; float f; } v; v.u = u & 0xffff0000u; return v.f;
}
// v_permlane32_swap_b32: a' = {a.lo32, b.lo32}; b' = {a.hi32, b.hi32}
__device__ __forceinline__ void plswap(uint32_t &a, uint32_t &b) {
    asm volatile("v_permlane32_swap_b32 %0, %1" : "+v"(a), "+v"(b));
}
typedef const __attribute__((address_space(1))) void* gptr_t;
typedef __attribute__((address_space(3))) void* lptr_t;
__device__ __forceinline__ void gl2lds16(const void* g, void* l) {
    __builtin_amdgcn_global_load_lds((gptr_t)g, (lptr_t)l, 16, 0, 0);
}

// ---------------------------------------------------------------------------
// Fused convert: z<4 -> W[z] fp32 [K][N] -> W^T [N][K] bf16 (z==0 scaled by
// log2e/8); z==4 -> x fp32 -> bf16 (grid-stride over the 4M plane).
// ---------------------------------------------------------------------------
__global__ __launch_bounds__(256) void cvt_all_k(
    const float* __restrict__ x,
    const float* __restrict__ W0, const float* __restrict__ W1,
    const float* __restrict__ W2, const float* __restrict__ W3,
    u16* __restrict__ Wt4, u16* __restrict__ xh) {
    const int z = blockIdx.z;
    const int tid = threadIdx.x;
    if (z == 4) {
        const int nb = gridDim.x * gridDim.y;
        const int bid = blockIdx.y * gridDim.x + blockIdx.x;
        const int stride = nb * 256 * 8;
        for (int i = (bid * 256 + tid) * 8; i < MROWS * EMB; i += stride) {
            float4 a = *(const float4*)(x + i);
            float4 b = *(const float4*)(x + i + 4);
            alignas(16) u16 o[8] = {f2bf(a.x), f2bf(a.y), f2bf(a.z), f2bf(a.w),
                                    f2bf(b.x), f2bf(b.y), f2bf(b.z), f2bf(b.w)};
            *(uint4*)(xh + i) = *(const uint4*)o;
        }
        return;
    }
    const float* W = (z == 0) ? W0 : (z == 1) ? W1 : (z == 2) ? W2 : W3;
    const float scale = (z == 0) ? 0.125f * LOG2E : 1.0f;
    u16* dst = Wt4 + (size_t)z * 1048576;
    __shared__ float Lf[64][65];
    const int kt = blockIdx.y * 64, nt = blockIdx.x * 64;
    {
        const int r = tid >> 2, c4 = (tid & 3) * 16;
        const float* src = W + (size_t)(kt + r) * EMB + nt + c4;
        #pragma unroll
        for (int i = 0; i < 16; i += 4) {
            float4 v = *(const float4*)(src + i);
            Lf[r][c4 + i + 0] = v.x; Lf[r][c4 + i + 1] = v.y;
            Lf[r][c4 + i + 2] = v.z; Lf[r][c4 + i + 3] = v.w;
        }
    }
    __syncthreads();
    const int n = tid >> 2, k4 = (tid & 3) * 16;
    alignas(16) u16 hb[16];
    #pragma unroll
    for (int i = 0; i < 16; ++i) hb[i] = f2bf(Lf[k4 + i][n] * scale);
    const size_t o = (size_t)(nt + n) * EMB + kt + k4;
    *(uint4*)(dst + o) = *(const uint4*)hb;
    *(uint4*)(dst + o + 8) = *(const uint4*)(hb + 8);
}

// ---------------------------------------------------------------------------
// QKV GEMM: 128x128 tile, BK=32, double-buffered (1 barrier/iter).
// XCD chunk remap (value-identical block->tile permutation).
// z==2 (V) epilogue writes DIRECTLY transposed to Vt[b][h][d][s] (same f2bf
// values, different addresses -> bit-identical; vtrans_k kernel eliminated).
// ---------------------------------------------------------------------------
__global__ __launch_bounds__(256) void gemm_qkv_k(
    const u16* __restrict__ xh, const u16* __restrict__ Wt4,
    const float* __restrict__ b0, const float* __restrict__ b1,
    const float* __restrict__ b2,
    u16* __restrict__ Q, u16* __restrict__ K, u16* __restrict__ Vt) {
    const int flat = blockIdx.x + 8 * blockIdx.y + 256 * blockIdx.z;
    const int xcd = flat & 7, i6 = flat >> 3;       // i6: 0..95
    const int z = i6 >> 5, j = i6 & 31;             // z 0..2, j 0..31
    const int cm = xcd & 3, cn = xcd >> 2;
    const int bm = (cm * 8 + (j >> 2)) * 128;       // 32 bm tiles
    const int bn = (cn * 4 + (j & 3)) * 128;        // 8 bn tiles

    const u16* Wt = Wt4 + (size_t)z * 1048576;
    const float* bias = (z == 0) ? b0 : (z == 1) ? b1 : b2;
    u16* out = (z == 0) ? Q : (z == 1) ? K : Vt;
    const float bscale = (z == 0) ? 0.125f * LOG2E : 1.0f;
    __shared__ alignas(16) u16 As[2][4096];
    __shared__ alignas(16) u16 Bs[2][4096];
    const int tid = threadIdx.x;
    const int lane = tid & 63, w = tid >> 6;
    const int l15 = lane & 15, quad = lane >> 4;
    const int wm = (w & 1) * 64, wn = (w >> 1) * 64;

    floatx4 acc[4][4];
    const floatx4 zf = {0.f, 0.f, 0.f, 0.f};
    #pragma unroll
    for (int mt = 0; mt < 4; ++mt)
        #pragma unroll
        for (int nt = 0; nt < 4; ++nt) acc[mt][nt] = zf;

    const int c0 = tid, c1 = tid + 256;
    const int r0 = c0 >> 2, p0 = c0 & 3, cc0 = (p0 - r0 - (r0 >> 2)) & 3;
    const int r1 = c1 >> 2, p1 = c1 & 3, cc1 = (p1 - r1 - (r1 >> 2)) & 3;
    const u16* ag0 = xh + (size_t)(bm + r0) * EMB + cc0 * 8;
    const u16* ag1 = xh + (size_t)(bm + r1) * EMB + cc1 * 8;
    const u16* bg0 = Wt + (size_t)(bn + r0) * EMB + cc0 * 8;
    const u16* bg1 = Wt + (size_t)(bn + r1) * EMB + cc1 * 8;

    #define QSTAGE(bf, kk) do { \
        gl2lds16(ag0 + (kk), &As[bf][c0 * 8]); gl2lds16(ag1 + (kk), &As[bf][c1 * 8]); \
        gl2lds16(bg0 + (kk), &Bs[bf][c0 * 8]); gl2lds16(bg1 + (kk), &Bs[bf][c1 * 8]); } while (0)

    QSTAGE(0, 0);
    __syncthreads();
    for (int kt = 0; kt < EMB; kt += 32) {
        const int cur = (kt >> 5) & 1;
        if (kt + 32 < EMB) QSTAGE(cur ^ 1, kt + 32);
        short8 af[4], bf[4];
        #pragma unroll
        for (int t = 0; t < 4; ++t) {
            const int ra = wm + t * 16 + l15;
            const int rb = wn + t * 16 + l15;
            af[t] = *(const short8*)&As[cur][ra * 32 + ((quad + ra + (ra >> 2)) & 3) * 8];
            bf[t] = *(const short8*)&Bs[cur][rb * 32 + ((quad + rb + (rb >> 2)) & 3) * 8];
        }
        __builtin_amdgcn_s_setprio(1);
        #pragma unroll
        for (int mt = 0; mt < 4; ++mt)
            #pragma unroll
            for (int nt = 0; nt < 4; ++nt)
                acc[mt][nt] = MFMA32(af[mt], bf[nt], acc[mt][nt]);
        __builtin_amdgcn_s_setprio(0);
        __syncthreads();   // drains this iter's prefetch into buf cur^1
    }

    if (z == 2) {
        // transposed V store: Vt[b][h][d][s]; per lane 4 consecutive u16 = 8B
        #pragma unroll
        for (int nt = 0; nt < 4; ++nt) {
            const int col = bn + wn + nt * 16 + l15;   // h*64 + d
            const int hh = col >> 6, d = col & 63;
            const float bv = bias[col] * bscale;
            #pragma unroll
            for (int mt = 0; mt < 4; ++mt) {
                const int row = bm + wm + mt * 16 + quad * 4;   // b*SEQ + s
                const int bb = row >> 11, s = row & 2047;
                alignas(8) u16 o4[4];
                #pragma unroll
                for (int r = 0; r < 4; ++r) o4[r] = f2bf(acc[mt][nt][r] + bv);
                *(uint2*)(out + ((size_t)((bb * NH + hh) * HD + d)) * SEQ + s) =
                    *(const uint2*)o4;
            }
        }
    } else {
        #pragma unroll
        for (int nt = 0; nt < 4; ++nt) {
            const int col = bn + wn + nt * 16 + l15;
            const float bv = bias[col] * bscale;
            #pragma unroll
            for (int mt = 0; mt < 4; ++mt) {
                const int row = bm + wm + mt * 16 + quad * 4;
                #pragma unroll
                for (int r = 0; r < 4; ++r)
                    out[(size_t)(row + r) * EMB + col] = f2bf(acc[mt][nt][r] + bv);
            }
        }
    }
}

// ---------------------------------------------------------------------------
// O-projection: 128x64 tile, BK=32, double-buffered, fp32 out + bias.
// XCD chunk remap (value-identical): 8bm x 8bn per XCD.
// ---------------------------------------------------------------------------
__global__ __launch_bounds__(256) void gemm_o_k(
    const u16* __restrict__ Ag, const u16* __restrict__ Wt,
    const float* __restrict__ bias, float* __restrict__ out) {
    const int flat = blockIdx.x + 16 * blockIdx.y;  // grid (16,32,1)
    const int xcd = flat & 7, i6 = flat >> 3;       // i6: 0..63
    const int cm = xcd & 3, cn = xcd >> 2;
    const int bm = (cm * 8 + (i6 >> 3)) * 128;      // 32 bm tiles
    const int bn = (cn * 8 + (i6 & 7)) * 64;        // 16 bn tiles
    __shared__ alignas(16) u16 As[2][4096];   // 128 x 32 x2
    __shared__ alignas(16) u16 Bs[2][2048];   // 64 x 32 x2
    const int tid = threadIdx.x;
    const int lane = tid & 63, w = tid >> 6;
    const int l15 = lane & 15, quad = lane >> 4;
    const int wm = w * 32;

    floatx4 acc[2][4];
    const floatx4 zf = {0.f, 0.f, 0.f, 0.f};
    #pragma unroll
    for (int mt = 0; mt < 2; ++mt)
        #pragma unroll
        for (int nt = 0; nt < 4; ++nt) acc[mt][nt] = zf;

    const int c0 = tid, c1 = tid + 256;
    const int r0 = c0 >> 2, p0 = c0 & 3, cc0 = (p0 - r0 - (r0 >> 2)) & 3;
    const int r1 = c1 >> 2, p1 = c1 & 3, cc1 = (p1 - r1 - (r1 >> 2)) & 3;
    const u16* ag0 = Ag + (size_t)(bm + r0) * EMB + cc0 * 8;
    const u16* ag1 = Ag + (size_t)(bm + r1) * EMB + cc1 * 8;
    const u16* bg0 = Wt + (size_t)(bn + r0) * EMB + cc0 * 8;   // first 256 slots

    #define OSTAGE(bf, kk) do { \
        gl2lds16(ag0 + (kk), &As[bf][c0 * 8]); \
        gl2lds16(ag1 + (kk), &As[bf][c1 * 8]); \
        if (c0 < 256) gl2lds16(bg0 + (kk), &Bs[bf][c0 * 8]); } while (0)

    OSTAGE(0, 0);
    __syncthreads();
    for (int kt = 0; kt < EMB; kt += 32) {
        const int cur = (kt >> 5) & 1;
        if (kt + 32 < EMB) OSTAGE(cur ^ 1, kt + 32);
        short8 af[2], bf[4];
        #pragma unroll
        for (int t = 0; t < 2; ++t) {
            const int ra = wm + t * 16 + l15;
            af[t] = *(const short8*)&As[cur][ra * 32 + ((quad + ra + (ra >> 2)) & 3) * 8];
        }
        #pragma unroll
        for (int t = 0; t < 4; ++t) {
            const int rb = t * 16 + l15;
            bf[t] = *(const short8*)&Bs[cur][rb * 32 + ((quad + rb + (rb >> 2)) & 3) * 8];
        }
        __builtin_amdgcn_s_setprio(1);
        #pragma unroll
        for (int mt = 0; mt < 2; ++mt)
            #pragma unroll
            for (int nt = 0; nt < 4; ++nt)
                acc[mt][nt] = MFMA32(af[mt], bf[nt], acc[mt][nt]);
        __builtin_amdgcn_s_setprio(0);
        __syncthreads();
    }

    #pragma unroll
    for (int nt = 0; nt < 4; ++nt) {
        const int col = bn + nt * 16 + l15;
        const float bv = bias[col];
        #pragma unroll
        for (int mt = 0; mt < 2; ++mt) {
            const int row = bm + wm + mt * 16 + quad * 4;
            #pragma unroll
            for (int r = 0; r < 4; ++r)
                out[(size_t)(row + r) * EMB + col] = acc[mt][nt][r] + bv;
        }
    }
}

// ---------------------------------------------------------------------------
// Flash attention v13: round-5 passing numerics verbatim (split-K x4, bf16
// partials, ones-MFMA l, packed Schraudolph, setprio, XCD group remap) but
// SINGLE-buffered K/V staging (16KB LDS): round-1 A/B showed single-buf 51.9
// vs dbuf 55.2 us -- dbuf's occupancy cost (5 blocks/CU) exceeds its stall
// savings. Same staged values/order -> bit-identical output.
// ---------------------------------------------------------------------------
__global__ __launch_bounds__(256) void flash_k(
    const u16* __restrict__ Q, const u16* __restrict__ K,
    const u16* __restrict__ Vt,
    u16* __restrict__ Np0, u16* __restrict__ Np1,
    u16* __restrict__ Np2, u16* __restrict__ Np3,
    float* __restrict__ Lp) {
    // flat = bx + 16*by + 256*bz (HW dispatch order); xcd = flat%8
    const int flat = blockIdx.x + 16 * blockIdx.y + 256 * blockIdx.z;
    const int xcd = flat & 7, idx = flat >> 3;       // idx 0..255
    const int gid = xcd * 16 + (idx >> 4);           // group 0..127 = (h,b,sp)
    const int qt = idx & 15;
    const int h = gid & 15, zz = gid >> 4;           // zz 0..7
    const int b = zz >> 2, sp = zz & 3;
    const int t0 = sp * (SEQ / 4);
    __shared__ alignas(16) u16 Ks[4096];   // [t64][d64] 128B rows, swizzled
    __shared__ alignas(16) u16 Vs[4096];   // [d64][t64] 128B rows, swizzled
    const int tid = threadIdx.x;
    const int lane = tid & 63, w = tid >> 6;
    const int l31 = lane & 31, hf = lane >> 5;

    // Q B-frags: qb[c][j] = Q[q][h*64 + c*16 + hf*8 + j], q = qt*128+w*32+l31
    const u16* qp = Q + (size_t)(b * SEQ + qt * 128 + w * 32 + l31) * EMB
                    + h * HD + hf * 8;
    short8 qb[4];
    #pragma unroll
    for (int c = 0; c < 4; ++c) qb[c] = *(const short8*)(qp + c * 16);

    const floatx16 z16 = {0.f, 0.f, 0.f, 0.f, 0.f, 0.f, 0.f, 0.f,
                          0.f, 0.f, 0.f, 0.f, 0.f, 0.f, 0.f, 0.f};
    floatx16 oacc[2];
    oacc[0] = z16; oacc[1] = z16;
    floatx16 lacc = z16;
    const short8 ones8 = {0x3F80, 0x3F80, 0x3F80, 0x3F80,
                          0x3F80, 0x3F80, 0x3F80, 0x3F80};   // bf16 1.0

    // staging: slot s -> row r=s>>3, pos p=s&7, source chunk c=(p-r)&7
    const int s0 = tid, s1 = tid + 256;
    const int kr0 = s0 >> 3, kc0 = ((s0 & 7) - kr0) & 7;
    const int kr1 = s1 >> 3, kc1 = ((s1 & 7) - kr1) & 7;
    const u16* kg0 = K + (size_t)(b * SEQ + t0 + kr0) * EMB + h * HD + kc0 * 8;
    const u16* kg1 = K + (size_t)(b * SEQ + t0 + kr1) * EMB + h * HD + kc1 * 8;
    const u16* vg0 = Vt + ((size_t)((b * NH + h) * HD + kr0)) * SEQ + t0 + kc0 * 8;
    const u16* vg1 = Vt + ((size_t)((b * NH + h) * HD + kr1)) * SEQ + t0 + kc1 * 8;

    #define FSTAGE(kk) do { \
        gl2lds16(kg0 + (size_t)(kk) * 64 * EMB, &Ks[s0 * 8]); \
        gl2lds16(kg1 + (size_t)(kk) * 64 * EMB, &Ks[s1 * 8]); \
        gl2lds16(vg0 + (kk) * 64, &Vs[s0 * 8]); \
        gl2lds16(vg1 + (kk) * 64, &Vs[s1 * 8]); } while (0)

    const int NT = SEQ / 4 / 64;   // 8
    for (int kt = 0; kt < NT; ++kt) {
        __syncthreads();
        FSTAGE(kt);
        __syncthreads();

        // St = K Q^T per 32-t tile; exp; pack PV A-frags pa[g] (t=g*16..+15)
        short8 pa[4];
        #pragma unroll
        for (int tt = 0; tt < 2; ++tt) {
            floatx16 st = z16;
            const int r = tt * 32 + l31;
            __builtin_amdgcn_s_setprio(1);
            #pragma unroll
            for (int c = 0; c < 4; ++c) {
                const int jc = c * 2 + hf;
                const short8 ka = *(const short8*)&Ks[r * 64 + ((jc + r) & 7) * 8];
                st = MFMA3216(ka, qb[c], st);
            }
            __builtin_amdgcn_s_setprio(0);
            // packed Schraudolph 2^s: bits = (int)(s*2^23 + C) via v_pk_fma
            uint32_t e[16];
            #pragma unroll
            for (int i = 0; i < 16; i += 2) {
                f32x2 v = {st[i], st[i + 1]};
                v = v * 8388608.0f + 1064992512.0f;
                e[i] = (uint32_t)(int)v.x;
                e[i + 1] = (uint32_t)(int)v.y;
            }
            #pragma unroll
            for (int c = 0; c < 2; ++c) {
                uint32_t w0 = pk2u(e[c * 8 + 0], e[c * 8 + 1]);
                uint32_t w1 = pk2u(e[c * 8 + 2], e[c * 8 + 3]);
                uint32_t w2 = pk2u(e[c * 8 + 4], e[c * 8 + 5]);
                uint32_t w3 = pk2u(e[c * 8 + 6], e[c * 8 + 7]);
                plswap(w0, w2);   // -> word0, word2
                plswap(w1, w3);   // -> word1, word3
                union { uint32_t uu[4]; short8 s; } pk_;
                pk_.uu[0] = w0; pk_.uu[1] = w1; pk_.uu[2] = w2; pk_.uu[3] = w3;
                pa[tt * 2 + c] = pk_.s;
            }
        }

        // O += P^T V ; l += P^T 1 (ones-MFMA: same truncated bits as numerator)
        __builtin_amdgcn_s_setprio(1);
        #pragma unroll
        for (int dt = 0; dt < 2; ++dt) {
            const int vr = dt * 32 + l31;
            #pragma unroll
            for (int g = 0; g < 4; ++g) {
                const int jc = g * 2 + hf;
                const short8 vb = *(const short8*)&Vs[vr * 64 + ((jc + vr) & 7) * 8];
                oacc[dt] = MFMA3216(pa[g], vb, oacc[dt]);
            }
        }
        #pragma unroll
        for (int g = 0; g < 4; ++g) lacc = MFMA3216(pa[g], ones8, lacc);
        __builtin_amdgcn_s_setprio(0);
    }

    u16* np = (sp == 0) ? Np0 : (sp == 1) ? Np1 : (sp == 2) ? Np2 : Np3;
    float* lp = Lp + (size_t)sp * (MROWS * NH);

    // l store: lacc rows are col-replicated; lanes with l31==0 own all 16 rows
    if (l31 == 0) {
        #pragma unroll
        for (int r = 0; r < 16; ++r) {
            const int qloc = (r & 3) + 8 * (r >> 2) + 4 * hf;
            const int qrow = qt * 128 + w * 32 + qloc;
            lp[(size_t)(b * SEQ + qrow) * NH + h] = lacc[r];
        }
    }

    // numerator: C layout col=l31 (d), row=(r&3)+8*(r>>2)+4*hf (q)
    #pragma unroll
    for (int dt = 0; dt < 2; ++dt)
        #pragma unroll
        for (int r = 0; r < 16; ++r) {
            const int qloc = (r & 3) + 8 * (r >> 2) + 4 * hf;
            const size_t o =
                (size_t)(b * SEQ + qt * 128 + w * 32 + qloc) * EMB
                + h * HD + dt * 32 + l31;
            np[o] = f2bf(oacc[dt][r]);
        }
}

// ---------------------------------------------------------------------------
// Combine 4 split-K partials: AO = (N0+N1+N2+N3)/(l0+l1+l2+l3), bf16 out
// ---------------------------------------------------------------------------
__global__ __launch_bounds__(256) void reduce_k(
    const u16* __restrict__ Np0, const u16* __restrict__ Np1,
    const u16* __restrict__ Np2, const u16* __restrict__ Np3,
    const float* __restrict__ Lp, u16* __restrict__ AO) {
    const int i = blockIdx.x * 256 + threadIdx.x;   // 0 .. 1M-1
    const int e = i * 4;
    const int row = e >> 10;
    const int hh = (e & 1023) >> 6;
    const size_t lx = (size_t)row * NH + hh;
    const float lsum = Lp[lx] + Lp[(size_t)(MROWS * NH) + lx] +
                       Lp[2 * (size_t)(MROWS * NH) + lx] +
                       Lp[3 * (size_t)(MROWS * NH) + lx];
    const float inv = 1.f / lsum;
    const uint2 n0 = *(const uint2*)(Np0 + e);
    const uint2 n1 = *(const uint2*)(Np1 + e);
    const uint2 n2 = *(const uint2*)(Np2 + e);
    const uint2 n3 = *(const uint2*)(Np3 + e);
    const float x0 = (lo_f(n0.x) + lo_f(n1.x) + lo_f(n2.x) + lo_f(n3.x)) * inv;
    const float x1 = (hi_f(n0.x) + hi_f(n1.x) + hi_f(n2.x) + hi_f(n3.x)) * inv;
    const float x2 = (lo_f(n0.y) + lo_f(n1.y) + lo_f(n2.y) + lo_f(n3.y)) * inv;
    const float x3 = (hi_f(n0.y) + hi_f(n1.y) + hi_f(n2.y) + hi_f(n3.y)) * inv;
    uint2 o;
    o.x = (uint32_t)f2bf(x0) | ((uint32_t)f2bf(x1) << 16);
    o.y = (uint32_t)f2bf(x2) | ((uint32_t)f2bf(x3) << 16);
    *(uint2*)(AO + e) = o;
}

// ---------------------------------------------------------------------------
extern "C" void kernel_launch(void* const* d_in, const int* in_sizes, int n_in,
                              void* d_out, int out_size, void* d_ws, size_t ws_size,
                              hipStream_t stream) {
    const float* x  = (const float*)d_in[0];
    const float* Wq = (const float*)d_in[1];
    const float* bq = (const float*)d_in[2];
    const float* Wk = (const float*)d_in[3];
    const float* bk = (const float*)d_in[4];
    const float* Wv = (const float*)d_in[5];
    const float* bv = (const float*)d_in[6];
    const float* Wo = (const float*)d_in[7];
    const float* bo = (const float*)d_in[8];

    u16* ws16 = (u16*)d_ws;
    const size_t P4 = (size_t)MROWS * EMB;   // 4M elems (8 MB)
    u16* xh  = ws16;                 // x bf16; dead after gemm_qkv -> N0
    u16* Qb  = ws16 + P4;            // Q; dead after flash -> AO
    u16* Kb  = ws16 + 2 * P4;
    u16* Vb  = ws16 + 3 * P4;        // scratch: N1 home (V row-major no longer exists)
    u16* Vtb = ws16 + 4 * P4;        // V transposed [B][H][D][S] (written by gemm_qkv)
    u16* Wt4 = ws16 + 5 * P4;        // 4 planes of 1M: Wq^T*log2e/8, Wk^T, Wv^T, Wo^T
    u16* N2  = ws16 + 6 * P4;
    u16* N3  = ws16 + 7 * P4;
    float* Lp = (float*)(ws16 + 8 * P4);   // 4 x 65536 floats (1 MB)

    cvt_all_k<<<dim3(16, 16, 5), 256, 0, stream>>>(x, Wq, Wk, Wv, Wo, Wt4, xh);
    gemm_qkv_k<<<dim3(8, 32, 3), 256, 0, stream>>>(xh, Wt4, bq, bk, bv, Qb, Kb, Vtb);
    flash_k<<<dim3(16, 16, 8), 256, 0, stream>>>(Qb, Kb, Vtb, xh, Vb, N2, N3, Lp);
    reduce_k<<<4096, 256, 0, stream>>>(xh, Vb, N2, N3, Lp, Qb);
    gemm_o_k<<<dim3(16, 32, 1), 256, 0, stream>>>(Qb, Wt4 + 3 * 1048576, bo, (float*)d_out);
}

// Round 9
// 202.366 us; speedup vs baseline: 1.1775x; 1.0497x over previous
//
#include <hip/hip_runtime.h>
#include <cstddef>
#include <cstdint>

#define EMB 1024
#define NH 16
#define HD 64
#define SEQ 2048
#define BATCH 2
#define MROWS 4096
#define LOG2E 1.4426950408889634f

typedef unsigned short u16;
typedef __attribute__((ext_vector_type(8))) short short8;
typedef __attribute__((ext_vector_type(4))) float floatx4;
typedef __attribute__((ext_vector_type(16))) float floatx16;
typedef __attribute__((ext_vector_type(2))) float f32x2;

#define MFMA32(a,b,c) __builtin_amdgcn_mfma_f32_16x16x32_bf16((a),(b),(c),0,0,0)
#define MFMA3216(a,b,c) __builtin_amdgcn_mfma_f32_32x32x16_bf16((a),(b),(c),0,0,0)

__device__ __forceinline__ u16 f2bf(float f) {           // RNE
    union { float f; uint32_t u; } v; v.f = f;
    return (u16)((v.u + 0x7fffu + ((v.u >> 16) & 1u)) >> 16);
}
// pack top-16-bits(a) (lo) | top-16-bits(b) (hi) in one v_perm
__device__ __forceinline__ uint32_t pk2u(uint32_t a, uint32_t b) {
    return __builtin_amdgcn_perm(b, a, 0x07060302u);
}
__device__ __forceinline__ float lo_f(uint32_t u) {
    union { uint32_t u; float f; } v; v.u = u << 16; return v.f;
}
__device__ __forceinline__ float hi_f(uint32_t u) {
    union { uint32_t u; float f; } v; v.u = u & 0xffff0000u; return v.f;
}
// v_permlane32_swap_b32: a' = {a.lo32, b.lo32}; b' = {a.hi32, b.hi32}
__device__ __forceinline__ void plswap(uint32_t &a, uint32_t &b) {
    asm volatile("v_permlane32_swap_b32 %0, %1" : "+v"(a), "+v"(b));
}
typedef const __attribute__((address_space(1))) void* gptr_t;
typedef __attribute__((address_space(3))) void* lptr_t;
__device__ __forceinline__ void gl2lds16(const void* g, void* l) {
    __builtin_amdgcn_global_load_lds((gptr_t)g, (lptr_t)l, 16, 0, 0);
}

// ---------------------------------------------------------------------------
// Fused convert: z<4 -> W[z] fp32 [K][N] -> W^T [N][K] bf16 (z==0 scaled by
// log2e/8); z==4 -> x fp32 -> bf16 (grid-stride over the 4M plane).
// ---------------------------------------------------------------------------
__global__ __launch_bounds__(256) void cvt_all_k(
    const float* __restrict__ x,
    const float* __restrict__ W0, const float* __restrict__ W1,
    const float* __restrict__ W2, const float* __restrict__ W3,
    u16* __restrict__ Wt4, u16* __restrict__ xh) {
    const int z = blockIdx.z;
    const int tid = threadIdx.x;
    if (z == 4) {
        const int nb = gridDim.x * gridDim.y;
        const int bid = blockIdx.y * gridDim.x + blockIdx.x;
        const int stride = nb * 256 * 8;
        for (int i = (bid * 256 + tid) * 8; i < MROWS * EMB; i += stride) {
            float4 a = *(const float4*)(x + i);
            float4 b = *(const float4*)(x + i + 4);
            alignas(16) u16 o[8] = {f2bf(a.x), f2bf(a.y), f2bf(a.z), f2bf(a.w),
                                    f2bf(b.x), f2bf(b.y), f2bf(b.z), f2bf(b.w)};
            *(uint4*)(xh + i) = *(const uint4*)o;
        }
        return;
    }
    const float* W = (z == 0) ? W0 : (z == 1) ? W1 : (z == 2) ? W2 : W3;
    const float scale = (z == 0) ? 0.125f * LOG2E : 1.0f;
    u16* dst = Wt4 + (size_t)z * 1048576;
    __shared__ float Lf[64][65];
    const int kt = blockIdx.y * 64, nt = blockIdx.x * 64;
    {
        const int r = tid >> 2, c4 = (tid & 3) * 16;
        const float* src = W + (size_t)(kt + r) * EMB + nt + c4;
        #pragma unroll
        for (int i = 0; i < 16; i += 4) {
            float4 v = *(const float4*)(src + i);
            Lf[r][c4 + i + 0] = v.x; Lf[r][c4 + i + 1] = v.y;
            Lf[r][c4 + i + 2] = v.z; Lf[r][c4 + i + 3] = v.w;
        }
    }
    __syncthreads();
    const int n = tid >> 2, k4 = (tid & 3) * 16;
    alignas(16) u16 hb[16];
    #pragma unroll
    for (int i = 0; i < 16; ++i) hb[i] = f2bf(Lf[k4 + i][n] * scale);
    const size_t o = (size_t)(nt + n) * EMB + kt + k4;
    *(uint4*)(dst + o) = *(const uint4*)hb;
    *(uint4*)(dst + o + 8) = *(const uint4*)(hb + 8);
}

// ---------------------------------------------------------------------------
// QKV GEMM: 128x128 tile, BK=32, double-buffered (1 barrier/iter).
// XCD chunk remap (value-identical block->tile permutation).
// ---------------------------------------------------------------------------
__global__ __launch_bounds__(256) void gemm_qkv_k(
    const u16* __restrict__ xh, const u16* __restrict__ Wt4,
    const float* __restrict__ b0, const float* __restrict__ b1,
    const float* __restrict__ b2,
    u16* __restrict__ Q, u16* __restrict__ K, u16* __restrict__ V) {
    const int flat = blockIdx.x + 8 * blockIdx.y + 256 * blockIdx.z;
    const int xcd = flat & 7, i6 = flat >> 3;       // i6: 0..95
    const int z = i6 >> 5, j = i6 & 31;             // z 0..2, j 0..31
    const int cm = xcd & 3, cn = xcd >> 2;
    const int bm = (cm * 8 + (j >> 2)) * 128;       // 32 bm tiles
    const int bn = (cn * 4 + (j & 3)) * 128;        // 8 bn tiles

    const u16* Wt = Wt4 + (size_t)z * 1048576;
    const float* bias = (z == 0) ? b0 : (z == 1) ? b1 : b2;
    u16* out = (z == 0) ? Q : (z == 1) ? K : V;
    const float bscale = (z == 0) ? 0.125f * LOG2E : 1.0f;
    __shared__ alignas(16) u16 As[2][4096];
    __shared__ alignas(16) u16 Bs[2][4096];
    const int tid = threadIdx.x;
    const int lane = tid & 63, w = tid >> 6;
    const int l15 = lane & 15, quad = lane >> 4;
    const int wm = (w & 1) * 64, wn = (w >> 1) * 64;

    floatx4 acc[4][4];
    const floatx4 zf = {0.f, 0.f, 0.f, 0.f};
    #pragma unroll
    for (int mt = 0; mt < 4; ++mt)
        #pragma unroll
        for (int nt = 0; nt < 4; ++nt) acc[mt][nt] = zf;

    const int c0 = tid, c1 = tid + 256;
    const int r0 = c0 >> 2, p0 = c0 & 3, cc0 = (p0 - r0 - (r0 >> 2)) & 3;
    const int r1 = c1 >> 2, p1 = c1 & 3, cc1 = (p1 - r1 - (r1 >> 2)) & 3;
    const u16* ag0 = xh + (size_t)(bm + r0) * EMB + cc0 * 8;
    const u16* ag1 = xh + (size_t)(bm + r1) * EMB + cc1 * 8;
    const u16* bg0 = Wt + (size_t)(bn + r0) * EMB + cc0 * 8;
    const u16* bg1 = Wt + (size_t)(bn + r1) * EMB + cc1 * 8;

    #define QSTAGE(bf, kk) do { \
        gl2lds16(ag0 + (kk), &As[bf][c0 * 8]); gl2lds16(ag1 + (kk), &As[bf][c1 * 8]); \
        gl2lds16(bg0 + (kk), &Bs[bf][c0 * 8]); gl2lds16(bg1 + (kk), &Bs[bf][c1 * 8]); } while (0)

    QSTAGE(0, 0);
    __syncthreads();
    for (int kt = 0; kt < EMB; kt += 32) {
        const int cur = (kt >> 5) & 1;
        if (kt + 32 < EMB) QSTAGE(cur ^ 1, kt + 32);
        short8 af[4], bf[4];
        #pragma unroll
        for (int t = 0; t < 4; ++t) {
            const int ra = wm + t * 16 + l15;
            const int rb = wn + t * 16 + l15;
            af[t] = *(const short8*)&As[cur][ra * 32 + ((quad + ra + (ra >> 2)) & 3) * 8];
            bf[t] = *(const short8*)&Bs[cur][rb * 32 + ((quad + rb + (rb >> 2)) & 3) * 8];
        }
        __builtin_amdgcn_s_setprio(1);
        #pragma unroll
        for (int mt = 0; mt < 4; ++mt)
            #pragma unroll
            for (int nt = 0; nt < 4; ++nt)
                acc[mt][nt] = MFMA32(af[mt], bf[nt], acc[mt][nt]);
        __builtin_amdgcn_s_setprio(0);
        __syncthreads();   // drains this iter's prefetch into buf cur^1
    }

    #pragma unroll
    for (int nt = 0; nt < 4; ++nt) {
        const int col = bn + wn + nt * 16 + l15;
        const float bv = bias[col] * bscale;
        #pragma unroll
        for (int mt = 0; mt < 4; ++mt) {
            const int row = bm + wm + mt * 16 + quad * 4;
            #pragma unroll
            for (int r = 0; r < 4; ++r)
                out[(size_t)(row + r) * EMB + col] = f2bf(acc[mt][nt][r] + bv);
        }
    }
}

// ---------------------------------------------------------------------------
// O-projection v2: 64x64 tile, BK=32, double-buffered, fp32 out + bias.
// Grid 1024 = 4 blocks/CU (was 512 = 2/CU at 128x64): 2x latency-hiding TLP
// for this latency-bound kernel (round-6 counters: MfmaUtil 4.5%, Occ 17.7%).
// Bit-identical: per-output-element MFMA accumulation chain unchanged.
// XCD chunk: 8 m-tiles x 16 n-tiles per XCD (A 1MB + B 2MB, L2-fits).
// ---------------------------------------------------------------------------
__global__ __launch_bounds__(256) void gemm_o_k(
    const u16* __restrict__ Ag, const u16* __restrict__ Wt,
    const float* __restrict__ bias, float* __restrict__ out) {
    const int flat = blockIdx.x + 16 * blockIdx.y;  // grid (16,64,1)
    const int xcd = flat & 7, i7 = flat >> 3;       // i7: 0..127
    const int bm = (xcd * 8 + (i7 >> 4)) * 64;      // 64 m-tiles
    const int bn = (i7 & 15) * 64;                  // 16 n-tiles
    __shared__ alignas(16) u16 As[2][2048];   // 64 x 32 x2
    __shared__ alignas(16) u16 Bs[2][2048];   // 64 x 32 x2
    const int tid = threadIdx.x;
    const int lane = tid & 63, w = tid >> 6;
    const int l15 = lane & 15, quad = lane >> 4;
    const int wm = (w & 1) * 32, wn = (w >> 1) * 32;

    floatx4 acc[2][2];
    const floatx4 zf = {0.f, 0.f, 0.f, 0.f};
    #pragma unroll
    for (int mt = 0; mt < 2; ++mt)
        #pragma unroll
        for (int nt = 0; nt < 2; ++nt) acc[mt][nt] = zf;

    const int c0 = tid;
    const int r0 = c0 >> 2, p0 = c0 & 3, cc0 = (p0 - r0 - (r0 >> 2)) & 3;
    const u16* ag0 = Ag + (size_t)(bm + r0) * EMB + cc0 * 8;
    const u16* bg0 = Wt + (size_t)(bn + r0) * EMB + cc0 * 8;

    #define OSTAGE(bf, kk) do { \
        gl2lds16(ag0 + (kk), &As[bf][c0 * 8]); \
        gl2lds16(bg0 + (kk), &Bs[bf][c0 * 8]); } while (0)

    OSTAGE(0, 0);
    __syncthreads();
    for (int kt = 0; kt < EMB; kt += 32) {
        const int cur = (kt >> 5) & 1;
        if (kt + 32 < EMB) OSTAGE(cur ^ 1, kt + 32);
        short8 af[2], bf[2];
        #pragma unroll
        for (int t = 0; t < 2; ++t) {
            const int ra = wm + t * 16 + l15;
            const int rb = wn + t * 16 + l15;
            af[t] = *(const short8*)&As[cur][ra * 32 + ((quad + ra + (ra >> 2)) & 3) * 8];
            bf[t] = *(const short8*)&Bs[cur][rb * 32 + ((quad + rb + (rb >> 2)) & 3) * 8];
        }
        __builtin_amdgcn_s_setprio(1);
        #pragma unroll
        for (int mt = 0; mt < 2; ++mt)
            #pragma unroll
            for (int nt = 0; nt < 2; ++nt)
                acc[mt][nt] = MFMA32(af[mt], bf[nt], acc[mt][nt]);
        __builtin_amdgcn_s_setprio(0);
        __syncthreads();
    }

    #pragma unroll
    for (int nt = 0; nt < 2; ++nt) {
        const int col = bn + wn + nt * 16 + l15;
        const float bv = bias[col];
        #pragma unroll
        for (int mt = 0; mt < 2; ++mt) {
            const int row = bm + wm + mt * 16 + quad * 4;
            #pragma unroll
            for (int r = 0; r < 4; ++r)
                out[(size_t)(row + r) * EMB + col] = acc[mt][nt][r] + bv;
        }
    }
}

// ---------------------------------------------------------------------------
// V [B*S][E] bf16 -> Vt [B][H][D][S] bf16 (coalesced via LDS)
// ---------------------------------------------------------------------------
__global__ __launch_bounds__(256) void vtrans_k(const u16* __restrict__ V,
                                                u16* __restrict__ Vt) {
    const int tt = blockIdx.x, h = blockIdx.y, b = blockIdx.z;
    __shared__ u16 Lt[64][72];
    const int tid = threadIdx.x;
    {
        const int r = tid >> 2, c4 = (tid & 3) * 16;
        const u16* src = V + (size_t)(b * SEQ + tt * 64 + r) * EMB + h * HD + c4;
        alignas(16) u16 buf[16];
        *(uint4*)buf = *(const uint4*)src;
        *(uint4*)(buf + 8) = *(const uint4*)(src + 8);
        #pragma unroll
        for (int i = 0; i < 16; ++i) Lt[c4 + i][r] = buf[i];
    }
    __syncthreads();
    const int d = tid >> 2, t4 = (tid & 3) * 16;
    u16* dst = Vt + ((size_t)((b * NH + h) * HD + d)) * SEQ + tt * 64 + t4;
    *(uint4*)dst = *(const uint4*)&Lt[d][t4];
    *(uint4*)(dst + 8) = *(const uint4*)&Lt[d][t4 + 8];
}

// ---------------------------------------------------------------------------
// Flash attention v12 (round-5 PASSING version, FROZEN): split-K x4 over t,
// bf16 partials, ones-MFMA l, packed Schraudolph, dbuf 1-barrier, XCD group
// remap. Three geometry restructures (rounds 3/4/8) failed numerically with
// an unexplained ~3e-3 signature -- do not restructure this kernel.
// ---------------------------------------------------------------------------
__global__ __launch_bounds__(256) void flash_k(
    const u16* __restrict__ Q, const u16* __restrict__ K,
    const u16* __restrict__ Vt,
    u16* __restrict__ Np0, u16* __restrict__ Np1,
    u16* __restrict__ Np2, u16* __restrict__ Np3,
    float* __restrict__ Lp) {
    // flat = bx + 16*by + 256*bz (HW dispatch order); xcd = flat%8
    const int flat = blockIdx.x + 16 * blockIdx.y + 256 * blockIdx.z;
    const int xcd = flat & 7, idx = flat >> 3;       // idx 0..255
    const int gid = xcd * 16 + (idx >> 4);           // group 0..127 = (h,b,sp)
    const int qt = idx & 15;
    const int h = gid & 15, zz = gid >> 4;           // zz 0..7
    const int b = zz >> 2, sp = zz & 3;
    const int t0 = sp * (SEQ / 4);
    __shared__ alignas(16) u16 Ks[2][4096];   // [t64][d64] 128B rows, swizzled
    __shared__ alignas(16) u16 Vs[2][4096];   // [d64][t64] 128B rows, swizzled
    const int tid = threadIdx.x;
    const int lane = tid & 63, w = tid >> 6;
    const int l31 = lane & 31, hf = lane >> 5;

    // Q B-frags: qb[c][j] = Q[q][h*64 + c*16 + hf*8 + j], q = qt*128+w*32+l31
    const u16* qp = Q + (size_t)(b * SEQ + qt * 128 + w * 32 + l31) * EMB
                    + h * HD + hf * 8;
    short8 qb[4];
    #pragma unroll
    for (int c = 0; c < 4; ++c) qb[c] = *(const short8*)(qp + c * 16);

    const floatx16 z16 = {0.f, 0.f, 0.f, 0.f, 0.f, 0.f, 0.f, 0.f,
                          0.f, 0.f, 0.f, 0.f, 0.f, 0.f, 0.f, 0.f};
    floatx16 oacc[2];
    oacc[0] = z16; oacc[1] = z16;
    floatx16 lacc = z16;
    const short8 ones8 = {0x3F80, 0x3F80, 0x3F80, 0x3F80,
                          0x3F80, 0x3F80, 0x3F80, 0x3F80};   // bf16 1.0

    // staging: slot s -> row r=s>>3, pos p=s&7, source chunk c=(p-r)&7
    const int s0 = tid, s1 = tid + 256;
    const int kr0 = s0 >> 3, kc0 = ((s0 & 7) - kr0) & 7;
    const int kr1 = s1 >> 3, kc1 = ((s1 & 7) - kr1) & 7;
    const u16* kg0 = K + (size_t)(b * SEQ + t0 + kr0) * EMB + h * HD + kc0 * 8;
    const u16* kg1 = K + (size_t)(b * SEQ + t0 + kr1) * EMB + h * HD + kc1 * 8;
    const u16* vg0 = Vt + ((size_t)((b * NH + h) * HD + kr0)) * SEQ + t0 + kc0 * 8;
    const u16* vg1 = Vt + ((size_t)((b * NH + h) * HD + kr1)) * SEQ + t0 + kc1 * 8;

    #define FSTAGE(bf, kk) do { \
        gl2lds16(kg0 + (size_t)(kk) * 64 * EMB, &Ks[bf][s0 * 8]); \
        gl2lds16(kg1 + (size_t)(kk) * 64 * EMB, &Ks[bf][s1 * 8]); \
        gl2lds16(vg0 + (kk) * 64, &Vs[bf][s0 * 8]); \
        gl2lds16(vg1 + (kk) * 64, &Vs[bf][s1 * 8]); } while (0)

    const int NT = SEQ / 4 / 64;   // 8
    FSTAGE(0, 0);
    __syncthreads();
    for (int kt = 0; kt < NT; ++kt) {
        const int cur = kt & 1;
        if (kt + 1 < NT) FSTAGE(cur ^ 1, kt + 1);

        // St = K Q^T per 32-t tile; exp; pack PV A-frags pa[g] (t=g*16..+15)
        short8 pa[4];
        #pragma unroll
        for (int tt = 0; tt < 2; ++tt) {
            floatx16 st = z16;
            const int r = tt * 32 + l31;
            __builtin_amdgcn_s_setprio(1);
            #pragma unroll
            for (int c = 0; c < 4; ++c) {
                const int jc = c * 2 + hf;
                const short8 ka = *(const short8*)&Ks[cur][r * 64 + ((jc + r) & 7) * 8];
                st = MFMA3216(ka, qb[c], st);
            }
            __builtin_amdgcn_s_setprio(0);
            // packed Schraudolph 2^s: bits = (int)(s*2^23 + C) via v_pk_fma
            uint32_t e[16];
            #pragma unroll
            for (int i = 0; i < 16; i += 2) {
                f32x2 v = {st[i], st[i + 1]};
                v = v * 8388608.0f + 1064992512.0f;
                e[i] = (uint32_t)(int)v.x;
                e[i + 1] = (uint32_t)(int)v.y;
            }
            #pragma unroll
            for (int c = 0; c < 2; ++c) {
                uint32_t w0 = pk2u(e[c * 8 + 0], e[c * 8 + 1]);
                uint32_t w1 = pk2u(e[c * 8 + 2], e[c * 8 + 3]);
                uint32_t w2 = pk2u(e[c * 8 + 4], e[c * 8 + 5]);
                uint32_t w3 = pk2u(e[c * 8 + 6], e[c * 8 + 7]);
                plswap(w0, w2);   // -> word0, word2
                plswap(w1, w3);   // -> word1, word3
                union { uint32_t uu[4]; short8 s; } pk_;
                pk_.uu[0] = w0; pk_.uu[1] = w1; pk_.uu[2] = w2; pk_.uu[3] = w3;
                pa[tt * 2 + c] = pk_.s;
            }
        }

        // O += P^T V ; l += P^T 1 (ones-MFMA: same truncated bits as numerator)
        __builtin_amdgcn_s_setprio(1);
        #pragma unroll
        for (int dt = 0; dt < 2; ++dt) {
            const int vr = dt * 32 + l31;
            #pragma unroll
            for (int g = 0; g < 4; ++g) {
                const int jc = g * 2 + hf;
                const short8 vb = *(const short8*)&Vs[cur][vr * 64 + ((jc + vr) & 7) * 8];
                oacc[dt] = MFMA3216(pa[g], vb, oacc[dt]);
            }
        }
        #pragma unroll
        for (int g = 0; g < 4; ++g) lacc = MFMA3216(pa[g], ones8, lacc);
        __builtin_amdgcn_s_setprio(0);

        __syncthreads();   // drains this iter's prefetch into buf cur^1
    }

    u16* np = (sp == 0) ? Np0 : (sp == 1) ? Np1 : (sp == 2) ? Np2 : Np3;
    float* lp = Lp + (size_t)sp * (MROWS * NH);

    // l store: lacc rows are col-replicated; lanes with l31==0 own all 16 rows
    if (l31 == 0) {
        #pragma unroll
        for (int r = 0; r < 16; ++r) {
            const int qloc = (r & 3) + 8 * (r >> 2) + 4 * hf;
            const int qrow = qt * 128 + w * 32 + qloc;
            lp[(size_t)(b * SEQ + qrow) * NH + h] = lacc[r];
        }
    }

    // numerator: C layout col=l31 (d), row=(r&3)+8*(r>>2)+4*hf (q)
    #pragma unroll
    for (int dt = 0; dt < 2; ++dt)
        #pragma unroll
        for (int r = 0; r < 16; ++r) {
            const int qloc = (r & 3) + 8 * (r >> 2) + 4 * hf;
            const size_t o =
                (size_t)(b * SEQ + qt * 128 + w * 32 + qloc) * EMB
                + h * HD + dt * 32 + l31;
            np[o] = f2bf(oacc[dt][r]);
        }
}

// ---------------------------------------------------------------------------
// Combine 4 split-K partials: AO = (N0+N1+N2+N3)/(l0+l1+l2+l3), bf16 out
// ---------------------------------------------------------------------------
__global__ __launch_bounds__(256) void reduce_k(
    const u16* __restrict__ Np0, const u16* __restrict__ Np1,
    const u16* __restrict__ Np2, const u16* __restrict__ Np3,
    const float* __restrict__ Lp, u16* __restrict__ AO) {
    const int i = blockIdx.x * 256 + threadIdx.x;   // 0 .. 1M-1
    const int e = i * 4;
    const int row = e >> 10;
    const int hh = (e & 1023) >> 6;
    const size_t lx = (size_t)row * NH + hh;
    const float lsum = Lp[lx] + Lp[(size_t)(MROWS * NH) + lx] +
                       Lp[2 * (size_t)(MROWS * NH) + lx] +
                       Lp[3 * (size_t)(MROWS * NH) + lx];
    const float inv = 1.f / lsum;
    const uint2 n0 = *(const uint2*)(Np0 + e);
    const uint2 n1 = *(const uint2*)(Np1 + e);
    const uint2 n2 = *(const uint2*)(Np2 + e);
    const uint2 n3 = *(const uint2*)(Np3 + e);
    const float x0 = (lo_f(n0.x) + lo_f(n1.x) + lo_f(n2.x) + lo_f(n3.x)) * inv;
    const float x1 = (hi_f(n0.x) + hi_f(n1.x) + hi_f(n2.x) + hi_f(n3.x)) * inv;
    const float x2 = (lo_f(n0.y) + lo_f(n1.y) + lo_f(n2.y) + lo_f(n3.y)) * inv;
    const float x3 = (hi_f(n0.y) + hi_f(n1.y) + hi_f(n2.y) + hi_f(n3.y)) * inv;
    uint2 o;
    o.x = (uint32_t)f2bf(x0) | ((uint32_t)f2bf(x1) << 16);
    o.y = (uint32_t)f2bf(x2) | ((uint32_t)f2bf(x3) << 16);
    *(uint2*)(AO + e) = o;
}

// ---------------------------------------------------------------------------
extern "C" void kernel_launch(void* const* d_in, const int* in_sizes, int n_in,
                              void* d_out, int out_size, void* d_ws, size_t ws_size,
                              hipStream_t stream) {
    const float* x  = (const float*)d_in[0];
    const float* Wq = (const float*)d_in[1];
    const float* bq = (const float*)d_in[2];
    const float* Wk = (const float*)d_in[3];
    const float* bk = (const float*)d_in[4];
    const float* Wv = (const float*)d_in[5];
    const float* bv = (const float*)d_in[6];
    const float* Wo = (const float*)d_in[7];
    const float* bo = (const float*)d_in[8];

    u16* ws16 = (u16*)d_ws;
    const size_t P4 = (size_t)MROWS * EMB;   // 4M elems (8 MB)
    u16* xh  = ws16;                 // x bf16; dead after gemm_qkv -> N0
    u16* Qb  = ws16 + P4;            // Q; dead after flash -> AO
    u16* Kb  = ws16 + 2 * P4;
    u16* Vb  = ws16 + 3 * P4;        // V row-major; dead after vtrans -> N1
    u16* Vtb = ws16 + 4 * P4;        // V transposed [B][H][D][S]
    u16* Wt4 = ws16 + 5 * P4;        // 4 planes of 1M: Wq^T*log2e/8, Wk^T, Wv^T, Wo^T
    u16* N2  = ws16 + 6 * P4;
    u16* N3  = ws16 + 7 * P4;
    float* Lp = (float*)(ws16 + 8 * P4);   // 4 x 65536 floats (1 MB)

    cvt_all_k<<<dim3(16, 16, 5), 256, 0, stream>>>(x, Wq, Wk, Wv, Wo, Wt4, xh);
    gemm_qkv_k<<<dim3(8, 32, 3), 256, 0, stream>>>(xh, Wt4, bq, bk, bv, Qb, Kb, Vb);
    vtrans_k<<<dim3(32, 16, 2), 256, 0, stream>>>(Vb, Vtb);
    flash_k<<<dim3(16, 16, 8), 256, 0, stream>>>(Qb, Kb, Vtb, xh, Vb, N2, N3, Lp);
    reduce_k<<<4096, 256, 0, stream>>>(xh, Vb, N2, N3, Lp, Qb);
    gemm_o_k<<<dim3(16, 64, 1), 256, 0, stream>>>(Qb, Wt4 + 3 * 1048576, bo, (float*)d_out);
}

// Round 10
// 198.272 us; speedup vs baseline: 1.2018x; 1.0207x over previous
//
#include <hip/hip_runtime.h>
#include <cstddef>
#include <cstdint>

#define EMB 1024
#define NH 16
#define HD 64
#define SEQ 2048
#define BATCH 2
#define MROWS 4096
#define LOG2E 1.4426950408889634f

typedef unsigned short u16;
typedef __attribute__((ext_vector_type(8))) short short8;
typedef __attribute__((ext_vector_type(4))) float floatx4;
typedef __attribute__((ext_vector_type(16))) float floatx16;
typedef __attribute__((ext_vector_type(2))) float f32x2;

#define MFMA32(a,b,c) __builtin_amdgcn_mfma_f32_16x16x32_bf16((a),(b),(c),0,0,0)
#define MFMA3216(a,b,c) __builtin_amdgcn_mfma_f32_32x32x16_bf16((a),(b),(c),0,0,0)

__device__ __forceinline__ u16 f2bf(float f) {           // RNE
    union { float f; uint32_t u; } v; v.f = f;
    return (u16)((v.u + 0x7fffu + ((v.u >> 16) & 1u)) >> 16);
}
// pack top-16-bits(a) (lo) | top-16-bits(b) (hi) in one v_perm
__device__ __forceinline__ uint32_t pk2u(uint32_t a, uint32_t b) {
    return __builtin_amdgcn_perm(b, a, 0x07060302u);
}
__device__ __forceinline__ float lo_f(uint32_t u) {
    union { uint32_t u; float f; } v; v.u = u << 16; return v.f;
}
__device__ __forceinline__ float hi_f(uint32_t u) {
    union { uint32_t u; float f; } v; v.u = u & 0xffff0000u; return v.f;
}
// v_permlane32_swap_b32: a' = {a.lo32, b.lo32}; b' = {a.hi32, b.hi32}
__device__ __forceinline__ void plswap(uint32_t &a, uint32_t &b) {
    asm volatile("v_permlane32_swap_b32 %0, %1" : "+v"(a), "+v"(b));
}
typedef const __attribute__((address_space(1))) void* gptr_t;
typedef __attribute__((address_space(3))) void* lptr_t;
__device__ __forceinline__ void gl2lds16(const void* g, void* l) {
    __builtin_amdgcn_global_load_lds((gptr_t)g, (lptr_t)l, 16, 0, 0);
}

// ---------------------------------------------------------------------------
// Fused convert: z<4 -> W[z] fp32 [K][N] -> W^T [N][K] bf16 (z==0 scaled by
// log2e/8); z==4 -> x fp32 -> bf16 (grid-stride over the 4M plane).
// ---------------------------------------------------------------------------
__global__ __launch_bounds__(256) void cvt_all_k(
    const float* __restrict__ x,
    const float* __restrict__ W0, const float* __restrict__ W1,
    const float* __restrict__ W2, const float* __restrict__ W3,
    u16* __restrict__ Wt4, u16* __restrict__ xh) {
    const int z = blockIdx.z;
    const int tid = threadIdx.x;
    if (z == 4) {
        const int nb = gridDim.x * gridDim.y;
        const int bid = blockIdx.y * gridDim.x + blockIdx.x;
        const int stride = nb * 256 * 8;
        for (int i = (bid * 256 + tid) * 8; i < MROWS * EMB; i += stride) {
            float4 a = *(const float4*)(x + i);
            float4 b = *(const float4*)(x + i + 4);
            alignas(16) u16 o[8] = {f2bf(a.x), f2bf(a.y), f2bf(a.z), f2bf(a.w),
                                    f2bf(b.x), f2bf(b.y), f2bf(b.z), f2bf(b.w)};
            *(uint4*)(xh + i) = *(const uint4*)o;
        }
        return;
    }
    const float* W = (z == 0) ? W0 : (z == 1) ? W1 : (z == 2) ? W2 : W3;
    const float scale = (z == 0) ? 0.125f * LOG2E : 1.0f;
    u16* dst = Wt4 + (size_t)z * 1048576;
    __shared__ float Lf[64][65];
    const int kt = blockIdx.y * 64, nt = blockIdx.x * 64;
    {
        const int r = tid >> 2, c4 = (tid & 3) * 16;
        const float* src = W + (size_t)(kt + r) * EMB + nt + c4;
        #pragma unroll
        for (int i = 0; i < 16; i += 4) {
            float4 v = *(const float4*)(src + i);
            Lf[r][c4 + i + 0] = v.x; Lf[r][c4 + i + 1] = v.y;
            Lf[r][c4 + i + 2] = v.z; Lf[r][c4 + i + 3] = v.w;
        }
    }
    __syncthreads();
    const int n = tid >> 2, k4 = (tid & 3) * 16;
    alignas(16) u16 hb[16];
    #pragma unroll
    for (int i = 0; i < 16; ++i) hb[i] = f2bf(Lf[k4 + i][n] * scale);
    const size_t o = (size_t)(nt + n) * EMB + kt + k4;
    *(uint4*)(dst + o) = *(const uint4*)hb;
    *(uint4*)(dst + o + 8) = *(const uint4*)(hb + 8);
}

// ---------------------------------------------------------------------------
// QKV GEMM v2: 128x128 tile, BK=64, SINGLE-buffer, 2 barriers/tile (stage ->
// drain -> compute): 32 MFMAs per staging window (was 16) amortize the vmcnt
// drain; barrier count unchanged. LDS 32KB (5 blocks/CU cap, 3 resident).
// Staging uses flash-style 128B-row swizzle: slot s -> row r=s>>3, pos p=s&7,
// chunk c=(p-r)&7; read pos=((kk*4+quad)+row)&7. Accumulation chain per
// output element identical (k ascending, same MFMA) -> bit-identical.
// XCD chunk remap (value-identical block->tile permutation).
// ---------------------------------------------------------------------------
__global__ __launch_bounds__(256) void gemm_qkv_k(
    const u16* __restrict__ xh, const u16* __restrict__ Wt4,
    const float* __restrict__ b0, const float* __restrict__ b1,
    const float* __restrict__ b2,
    u16* __restrict__ Q, u16* __restrict__ K, u16* __restrict__ V) {
    const int flat = blockIdx.x + 8 * blockIdx.y + 256 * blockIdx.z;
    const int xcd = flat & 7, i6 = flat >> 3;       // i6: 0..95
    const int z = i6 >> 5, j = i6 & 31;             // z 0..2, j 0..31
    const int cm = xcd & 3, cn = xcd >> 2;
    const int bm = (cm * 8 + (j >> 2)) * 128;       // 32 bm tiles
    const int bn = (cn * 4 + (j & 3)) * 128;        // 8 bn tiles

    const u16* Wt = Wt4 + (size_t)z * 1048576;
    const float* bias = (z == 0) ? b0 : (z == 1) ? b1 : b2;
    u16* out = (z == 0) ? Q : (z == 1) ? K : V;
    const float bscale = (z == 0) ? 0.125f * LOG2E : 1.0f;
    __shared__ alignas(16) u16 As[8192];   // 128 x 64
    __shared__ alignas(16) u16 Bs[8192];   // 128 x 64
    const int tid = threadIdx.x;
    const int lane = tid & 63, w = tid >> 6;
    const int l15 = lane & 15, quad = lane >> 4;
    const int wm = (w & 1) * 64, wn = (w >> 1) * 64;

    floatx4 acc[4][4];
    const floatx4 zf = {0.f, 0.f, 0.f, 0.f};
    #pragma unroll
    for (int mt = 0; mt < 4; ++mt)
        #pragma unroll
        for (int nt = 0; nt < 4; ++nt) acc[mt][nt] = zf;

    // staging addresses: 4 slots per thread per tile (1024 slots = 128r x 8c)
    const u16* agj[4];
    const u16* bgj[4];
    int sls[4];
    #pragma unroll
    for (int jj = 0; jj < 4; ++jj) {
        const int s = tid + 256 * jj;
        const int r = s >> 3, c = ((s & 7) - r) & 7;
        sls[jj] = s;
        agj[jj] = xh + (size_t)(bm + r) * EMB + c * 8;
        bgj[jj] = Wt + (size_t)(bn + r) * EMB + c * 8;
    }

    for (int kt = 0; kt < EMB; kt += 64) {
        __syncthreads();   // WAR: prior tile's reads done before overwrite
        #pragma unroll
        for (int jj = 0; jj < 4; ++jj) {
            gl2lds16(agj[jj] + kt, &As[sls[jj] * 8]);
            gl2lds16(bgj[jj] + kt, &Bs[sls[jj] * 8]);
        }
        __syncthreads();   // drain staging before reads
        #pragma unroll
        for (int kk = 0; kk < 2; ++kk) {
            short8 af[4], bf[4];
            #pragma unroll
            for (int t = 0; t < 4; ++t) {
                const int ra = wm + t * 16 + l15;
                const int rb = wn + t * 16 + l15;
                const int jc = kk * 4 + quad;
                af[t] = *(const short8*)&As[ra * 64 + ((jc + ra) & 7) * 8];
                bf[t] = *(const short8*)&Bs[rb * 64 + ((jc + rb) & 7) * 8];
            }
            __builtin_amdgcn_s_setprio(1);
            #pragma unroll
            for (int mt = 0; mt < 4; ++mt)
                #pragma unroll
                for (int nt = 0; nt < 4; ++nt)
                    acc[mt][nt] = MFMA32(af[mt], bf[nt], acc[mt][nt]);
            __builtin_amdgcn_s_setprio(0);
        }
    }

    #pragma unroll
    for (int nt = 0; nt < 4; ++nt) {
        const int col = bn + wn + nt * 16 + l15;
        const float bv = bias[col] * bscale;
        #pragma unroll
        for (int mt = 0; mt < 4; ++mt) {
            const int row = bm + wm + mt * 16 + quad * 4;
            #pragma unroll
            for (int r = 0; r < 4; ++r)
                out[(size_t)(row + r) * EMB + col] = f2bf(acc[mt][nt][r] + bv);
        }
    }
}

// ---------------------------------------------------------------------------
// O-projection: 64x64 tile, BK=32, double-buffered, fp32 out + bias.
// Grid 1024 = 4 blocks/CU. XCD chunk: 8 m-tiles x 16 n-tiles per XCD.
// ---------------------------------------------------------------------------
__global__ __launch_bounds__(256) void gemm_o_k(
    const u16* __restrict__ Ag, const u16* __restrict__ Wt,
    const float* __restrict__ bias, float* __restrict__ out) {
    const int flat = blockIdx.x + 16 * blockIdx.y;  // grid (16,64,1)
    const int xcd = flat & 7, i7 = flat >> 3;       // i7: 0..127
    const int bm = (xcd * 8 + (i7 >> 4)) * 64;      // 64 m-tiles
    const int bn = (i7 & 15) * 64;                  // 16 n-tiles
    __shared__ alignas(16) u16 As[2][2048];   // 64 x 32 x2
    __shared__ alignas(16) u16 Bs[2][2048];   // 64 x 32 x2
    const int tid = threadIdx.x;
    const int lane = tid & 63, w = tid >> 6;
    const int l15 = lane & 15, quad = lane >> 4;
    const int wm = (w & 1) * 32, wn = (w >> 1) * 32;

    floatx4 acc[2][2];
    const floatx4 zf = {0.f, 0.f, 0.f, 0.f};
    #pragma unroll
    for (int mt = 0; mt < 2; ++mt)
        #pragma unroll
        for (int nt = 0; nt < 2; ++nt) acc[mt][nt] = zf;

    const int c0 = tid;
    const int r0 = c0 >> 2, p0 = c0 & 3, cc0 = (p0 - r0 - (r0 >> 2)) & 3;
    const u16* ag0 = Ag + (size_t)(bm + r0) * EMB + cc0 * 8;
    const u16* bg0 = Wt + (size_t)(bn + r0) * EMB + cc0 * 8;

    #define OSTAGE(bf, kk) do { \
        gl2lds16(ag0 + (kk), &As[bf][c0 * 8]); \
        gl2lds16(bg0 + (kk), &Bs[bf][c0 * 8]); } while (0)

    OSTAGE(0, 0);
    __syncthreads();
    for (int kt = 0; kt < EMB; kt += 32) {
        const int cur = (kt >> 5) & 1;
        if (kt + 32 < EMB) OSTAGE(cur ^ 1, kt + 32);
        short8 af[2], bf[2];
        #pragma unroll
        for (int t = 0; t < 2; ++t) {
            const int ra = wm + t * 16 + l15;
            const int rb = wn + t * 16 + l15;
            af[t] = *(const short8*)&As[cur][ra * 32 + ((quad + ra + (ra >> 2)) & 3) * 8];
            bf[t] = *(const short8*)&Bs[cur][rb * 32 + ((quad + rb + (rb >> 2)) & 3) * 8];
        }
        __builtin_amdgcn_s_setprio(1);
        #pragma unroll
        for (int mt = 0; mt < 2; ++mt)
            #pragma unroll
            for (int nt = 0; nt < 2; ++nt)
                acc[mt][nt] = MFMA32(af[mt], bf[nt], acc[mt][nt]);
        __builtin_amdgcn_s_setprio(0);
        __syncthreads();
    }

    #pragma unroll
    for (int nt = 0; nt < 2; ++nt) {
        const int col = bn + wn + nt * 16 + l15;
        const float bv = bias[col];
        #pragma unroll
        for (int mt = 0; mt < 2; ++mt) {
            const int row = bm + wm + mt * 16 + quad * 4;
            #pragma unroll
            for (int r = 0; r < 4; ++r)
                out[(size_t)(row + r) * EMB + col] = acc[mt][nt][r] + bv;
        }
    }
}

// ---------------------------------------------------------------------------
// V [B*S][E] bf16 -> Vt [B][H][D][S] bf16 (coalesced via LDS)
// ---------------------------------------------------------------------------
__global__ __launch_bounds__(256) void vtrans_k(const u16* __restrict__ V,
                                                u16* __restrict__ Vt) {
    const int tt = blockIdx.x, h = blockIdx.y, b = blockIdx.z;
    __shared__ u16 Lt[64][72];
    const int tid = threadIdx.x;
    {
        const int r = tid >> 2, c4 = (tid & 3) * 16;
        const u16* src = V + (size_t)(b * SEQ + tt * 64 + r) * EMB + h * HD + c4;
        alignas(16) u16 buf[16];
        *(uint4*)buf = *(const uint4*)src;
        *(uint4*)(buf + 8) = *(const uint4*)(src + 8);
        #pragma unroll
        for (int i = 0; i < 16; ++i) Lt[c4 + i][r] = buf[i];
    }
    __syncthreads();
    const int d = tid >> 2, t4 = (tid & 3) * 16;
    u16* dst = Vt + ((size_t)((b * NH + h) * HD + d)) * SEQ + tt * 64 + t4;
    *(uint4*)dst = *(const uint4*)&Lt[d][t4];
    *(uint4*)(dst + 8) = *(const uint4*)&Lt[d][t4 + 8];
}

// ---------------------------------------------------------------------------
// Flash attention v12 (round-5 PASSING version, FROZEN): split-K x4 over t,
// bf16 partials, ones-MFMA l, packed Schraudolph, dbuf 1-barrier, XCD group
// remap. Three geometry restructures (rounds 3/4/8) failed with a replay-
// divergence signature (JSON absmax 468 vs first-run ~3e-3) -- scheduling-
// sensitive race suspected. Do not restructure this kernel.
// ---------------------------------------------------------------------------
__global__ __launch_bounds__(256) void flash_k(
    const u16* __restrict__ Q, const u16* __restrict__ K,
    const u16* __restrict__ Vt,
    u16* __restrict__ Np0, u16* __restrict__ Np1,
    u16* __restrict__ Np2, u16* __restrict__ Np3,
    float* __restrict__ Lp) {
    // flat = bx + 16*by + 256*bz (HW dispatch order); xcd = flat%8
    const int flat = blockIdx.x + 16 * blockIdx.y + 256 * blockIdx.z;
    const int xcd = flat & 7, idx = flat >> 3;       // idx 0..255
    const int gid = xcd * 16 + (idx >> 4);           // group 0..127 = (h,b,sp)
    const int qt = idx & 15;
    const int h = gid & 15, zz = gid >> 4;           // zz 0..7
    const int b = zz >> 2, sp = zz & 3;
    const int t0 = sp * (SEQ / 4);
    __shared__ alignas(16) u16 Ks[2][4096];   // [t64][d64] 128B rows, swizzled
    __shared__ alignas(16) u16 Vs[2][4096];   // [d64][t64] 128B rows, swizzled
    const int tid = threadIdx.x;
    const int lane = tid & 63, w = tid >> 6;
    const int l31 = lane & 31, hf = lane >> 5;

    // Q B-frags: qb[c][j] = Q[q][h*64 + c*16 + hf*8 + j], q = qt*128+w*32+l31
    const u16* qp = Q + (size_t)(b * SEQ + qt * 128 + w * 32 + l31) * EMB
                    + h * HD + hf * 8;
    short8 qb[4];
    #pragma unroll
    for (int c = 0; c < 4; ++c) qb[c] = *(const short8*)(qp + c * 16);

    const floatx16 z16 = {0.f, 0.f, 0.f, 0.f, 0.f, 0.f, 0.f, 0.f,
                          0.f, 0.f, 0.f, 0.f, 0.f, 0.f, 0.f, 0.f};
    floatx16 oacc[2];
    oacc[0] = z16; oacc[1] = z16;
    floatx16 lacc = z16;
    const short8 ones8 = {0x3F80, 0x3F80, 0x3F80, 0x3F80,
                          0x3F80, 0x3F80, 0x3F80, 0x3F80};   // bf16 1.0

    // staging: slot s -> row r=s>>3, pos p=s&7, source chunk c=(p-r)&7
    const int s0 = tid, s1 = tid + 256;
    const int kr0 = s0 >> 3, kc0 = ((s0 & 7) - kr0) & 7;
    const int kr1 = s1 >> 3, kc1 = ((s1 & 7) - kr1) & 7;
    const u16* kg0 = K + (size_t)(b * SEQ + t0 + kr0) * EMB + h * HD + kc0 * 8;
    const u16* kg1 = K + (size_t)(b * SEQ + t0 + kr1) * EMB + h * HD + kc1 * 8;
    const u16* vg0 = Vt + ((size_t)((b * NH + h) * HD + kr0)) * SEQ + t0 + kc0 * 8;
    const u16* vg1 = Vt + ((size_t)((b * NH + h) * HD + kr1)) * SEQ + t0 + kc1 * 8;

    #define FSTAGE(bf, kk) do { \
        gl2lds16(kg0 + (size_t)(kk) * 64 * EMB, &Ks[bf][s0 * 8]); \
        gl2lds16(kg1 + (size_t)(kk) * 64 * EMB, &Ks[bf][s1 * 8]); \
        gl2lds16(vg0 + (kk) * 64, &Vs[bf][s0 * 8]); \
        gl2lds16(vg1 + (kk) * 64, &Vs[bf][s1 * 8]); } while (0)

    const int NT = SEQ / 4 / 64;   // 8
    FSTAGE(0, 0);
    __syncthreads();
    for (int kt = 0; kt < NT; ++kt) {
        const int cur = kt & 1;
        if (kt + 1 < NT) FSTAGE(cur ^ 1, kt + 1);

        // St = K Q^T per 32-t tile; exp; pack PV A-frags pa[g] (t=g*16..+15)
        short8 pa[4];
        #pragma unroll
        for (int tt = 0; tt < 2; ++tt) {
            floatx16 st = z16;
            const int r = tt * 32 + l31;
            __builtin_amdgcn_s_setprio(1);
            #pragma unroll
            for (int c = 0; c < 4; ++c) {
                const int jc = c * 2 + hf;
                const short8 ka = *(const short8*)&Ks[cur][r * 64 + ((jc + r) & 7) * 8];
                st = MFMA3216(ka, qb[c], st);
            }
            __builtin_amdgcn_s_setprio(0);
            // packed Schraudolph 2^s: bits = (int)(s*2^23 + C) via v_pk_fma
            uint32_t e[16];
            #pragma unroll
            for (int i = 0; i < 16; i += 2) {
                f32x2 v = {st[i], st[i + 1]};
                v = v * 8388608.0f + 1064992512.0f;
                e[i] = (uint32_t)(int)v.x;
                e[i + 1] = (uint32_t)(int)v.y;
            }
            #pragma unroll
            for (int c = 0; c < 2; ++c) {
                uint32_t w0 = pk2u(e[c * 8 + 0], e[c * 8 + 1]);
                uint32_t w1 = pk2u(e[c * 8 + 2], e[c * 8 + 3]);
                uint32_t w2 = pk2u(e[c * 8 + 4], e[c * 8 + 5]);
                uint32_t w3 = pk2u(e[c * 8 + 6], e[c * 8 + 7]);
                plswap(w0, w2);   // -> word0, word2
                plswap(w1, w3);   // -> word1, word3
                union { uint32_t uu[4]; short8 s; } pk_;
                pk_.uu[0] = w0; pk_.uu[1] = w1; pk_.uu[2] = w2; pk_.uu[3] = w3;
                pa[tt * 2 + c] = pk_.s;
            }
        }

        // O += P^T V ; l += P^T 1 (ones-MFMA: same truncated bits as numerator)
        __builtin_amdgcn_s_setprio(1);
        #pragma unroll
        for (int dt = 0; dt < 2; ++dt) {
            const int vr = dt * 32 + l31;
            #pragma unroll
            for (int g = 0; g < 4; ++g) {
                const int jc = g * 2 + hf;
                const short8 vb = *(const short8*)&Vs[cur][vr * 64 + ((jc + vr) & 7) * 8];
                oacc[dt] = MFMA3216(pa[g], vb, oacc[dt]);
            }
        }
        #pragma unroll
        for (int g = 0; g < 4; ++g) lacc = MFMA3216(pa[g], ones8, lacc);
        __builtin_amdgcn_s_setprio(0);

        __syncthreads();   // drains this iter's prefetch into buf cur^1
    }

    u16* np = (sp == 0) ? Np0 : (sp == 1) ? Np1 : (sp == 2) ? Np2 : Np3;
    float* lp = Lp + (size_t)sp * (MROWS * NH);

    // l store: lacc rows are col-replicated; lanes with l31==0 own all 16 rows
    if (l31 == 0) {
        #pragma unroll
        for (int r = 0; r < 16; ++r) {
            const int qloc = (r & 3) + 8 * (r >> 2) + 4 * hf;
            const int qrow = qt * 128 + w * 32 + qloc;
            lp[(size_t)(b * SEQ + qrow) * NH + h] = lacc[r];
        }
    }

    // numerator: C layout col=l31 (d), row=(r&3)+8*(r>>2)+4*hf (q)
    #pragma unroll
    for (int dt = 0; dt < 2; ++dt)
        #pragma unroll
        for (int r = 0; r < 16; ++r) {
            const int qloc = (r & 3) + 8 * (r >> 2) + 4 * hf;
            const size_t o =
                (size_t)(b * SEQ + qt * 128 + w * 32 + qloc) * EMB
                + h * HD + dt * 32 + l31;
            np[o] = f2bf(oacc[dt][r]);
        }
}

// ---------------------------------------------------------------------------
// Combine 4 split-K partials: AO = (N0+N1+N2+N3)/(l0+l1+l2+l3), bf16 out.
// v2: uint4 loads, 8 elems/thread (one head-block -> one lsum), grid 2048.
// Per-element math identical to v1 -> bit-identical.
// ---------------------------------------------------------------------------
__global__ __launch_bounds__(256) void reduce_k(
    const u16* __restrict__ Np0, const u16* __restrict__ Np1,
    const u16* __restrict__ Np2, const u16* __restrict__ Np3,
    const float* __restrict__ Lp, u16* __restrict__ AO) {
    const int i = blockIdx.x * 256 + threadIdx.x;   // 0 .. 512K-1
    const int e = i * 8;
    const int row = e >> 10;
    const int hh = (e & 1023) >> 6;
    const size_t lx = (size_t)row * NH + hh;
    const float lsum = Lp[lx] + Lp[(size_t)(MROWS * NH) + lx] +
                       Lp[2 * (size_t)(MROWS * NH) + lx] +
                       Lp[3 * (size_t)(MROWS * NH) + lx];
    const float inv = 1.f / lsum;
    const uint4 n0 = *(const uint4*)(Np0 + e);
    const uint4 n1 = *(const uint4*)(Np1 + e);
    const uint4 n2 = *(const uint4*)(Np2 + e);
    const uint4 n3 = *(const uint4*)(Np3 + e);
    uint4 o;
    #define RED1(q0, q1, q2, q3) \
        ((uint32_t)f2bf((lo_f(q0) + lo_f(q1) + lo_f(q2) + lo_f(q3)) * inv) | \
         ((uint32_t)f2bf((hi_f(q0) + hi_f(q1) + hi_f(q2) + hi_f(q3)) * inv) << 16))
    o.x = RED1(n0.x, n1.x, n2.x, n3.x);
    o.y = RED1(n0.y, n1.y, n2.y, n3.y);
    o.z = RED1(n0.z, n1.z, n2.z, n3.z);
    o.w = RED1(n0.w, n1.w, n2.w, n3.w);
    *(uint4*)(AO + e) = o;
}

// ---------------------------------------------------------------------------
extern "C" void kernel_launch(void* const* d_in, const int* in_sizes, int n_in,
                              void* d_out, int out_size, void* d_ws, size_t ws_size,
                              hipStream_t stream) {
    const float* x  = (const float*)d_in[0];
    const float* Wq = (const float*)d_in[1];
    const float* bq = (const float*)d_in[2];
    const float* Wk = (const float*)d_in[3];
    const float* bk = (const float*)d_in[4];
    const float* Wv = (const float*)d_in[5];
    const float* bv = (const float*)d_in[6];
    const float* Wo = (const float*)d_in[7];
    const float* bo = (const float*)d_in[8];

    u16* ws16 = (u16*)d_ws;
    const size_t P4 = (size_t)MROWS * EMB;   // 4M elems (8 MB)
    u16* xh  = ws16;                 // x bf16; dead after gemm_qkv -> N0
    u16* Qb  = ws16 + P4;            // Q; dead after flash -> AO
    u16* Kb  = ws16 + 2 * P4;
    u16* Vb  = ws16 + 3 * P4;        // V row-major; dead after vtrans -> N1
    u16* Vtb = ws16 + 4 * P4;        // V transposed [B][H][D][S]
    u16* Wt4 = ws16 + 5 * P4;        // 4 planes of 1M: Wq^T*log2e/8, Wk^T, Wv^T, Wo^T
    u16* N2  = ws16 + 6 * P4;
    u16* N3  = ws16 + 7 * P4;
    float* Lp = (float*)(ws16 + 8 * P4);   // 4 x 65536 floats (1 MB)

    cvt_all_k<<<dim3(16, 16, 5), 256, 0, stream>>>(x, Wq, Wk, Wv, Wo, Wt4, xh);
    gemm_qkv_k<<<dim3(8, 32, 3), 256, 0, stream>>>(xh, Wt4, bq, bk, bv, Qb, Kb, Vb);
    vtrans_k<<<dim3(32, 16, 2), 256, 0, stream>>>(Vb, Vtb);
    flash_k<<<dim3(16, 16, 8), 256, 0, stream>>>(Qb, Kb, Vtb, xh, Vb, N2, N3, Lp);
    reduce_k<<<2048, 256, 0, stream>>>(xh, Vb, N2, N3, Lp, Qb);
    gemm_o_k<<<dim3(16, 64, 1), 256, 0, stream>>>(Qb, Wt4 + 3 * 1048576, bo, (float*)d_out);
}